// Round 1
// baseline (129.524 us; speedup 1.0000x reference)
//
#include <hip/hip_runtime.h>

typedef unsigned short u16;
typedef unsigned int u32;
typedef __attribute__((ext_vector_type(8))) __bf16 bf16x8;
typedef __attribute__((ext_vector_type(4))) float f32x4;

constexpr int SEQ = 2048;
constexpr int EMBD = 1024;
constexpr int HD = 128;
constexpr int NB = 8;

__device__ inline u16 f2bf(float f) {
  u32 u = __builtin_bit_cast(u32, f);
  u += 0x7FFFu + ((u >> 16) & 1u);
  return (u16)(u >> 16);
}

__device__ inline f32x4 mfma16(bf16x8 a, bf16x8 b, f32x4 c) {
  return __builtin_amdgcn_mfma_f32_16x16x32_bf16(a, b, c, 0, 0, 0);
}

// Stage a row-major [R][C] bf16 tile into LDS with XOR swizzle (byte ^= (row&7)<<4).
template<int R, int C>
__device__ inline void stage_tile(u16* lds, const u16* __restrict__ g, int ldg) {
  constexpr int CH = (R * C) / (8 * 256);
  int t = threadIdx.x;
#pragma unroll
  for (int ch = 0; ch < CH; ++ch) {
    int lin = ch * 256 + t;
    int row = lin / (C / 8);
    int cc = lin % (C / 8);
    int byte = row * (C * 2) + cc * 16;
    byte ^= (row & 7) << 4;
    *reinterpret_cast<uint4*>(reinterpret_cast<char*>(lds) + byte) =
        *reinterpret_cast<const uint4*>(g + (size_t)row * ldg + cc * 8);
  }
}

// Same, but source is fp32 (converted to bf16 on the fly).
template<int R, int C>
__device__ inline void stage_tile_f32(u16* lds, const float* __restrict__ g, int ldg) {
  constexpr int CH = (R * C) / (8 * 256);
  int t = threadIdx.x;
#pragma unroll
  for (int ch = 0; ch < CH; ++ch) {
    int lin = ch * 256 + t;
    int row = lin / (C / 8);
    int cc = lin % (C / 8);
    const float* p = g + (size_t)row * ldg + cc * 8;
    float4 a = *reinterpret_cast<const float4*>(p);
    float4 b = *reinterpret_cast<const float4*>(p + 4);
    uint4 o;
    o.x = (u32)f2bf(a.x) | ((u32)f2bf(a.y) << 16);
    o.y = (u32)f2bf(a.z) | ((u32)f2bf(a.w) << 16);
    o.z = (u32)f2bf(b.x) | ((u32)f2bf(b.y) << 16);
    o.w = (u32)f2bf(b.z) | ((u32)f2bf(b.w) << 16);
    int byte = row * (C * 2) + cc * 16;
    byte ^= (row & 7) << 4;
    *reinterpret_cast<uint4*>(reinterpret_cast<char*>(lds) + byte) = o;
  }
}

// Read one 8-element (16B) MFMA operand fragment from a swizzled LDS tile.
// RB = row bytes (C*2).  elem must be a multiple of 8.
template<int RB>
__device__ inline bf16x8 frag_ld(const u16* lds, int row, int elem) {
  int byte = row * RB + elem * 2;
  byte ^= (row & 7) << 4;
  return *reinterpret_cast<const bf16x8*>(reinterpret_cast<const char*>(lds) + byte);
}

// ---------------- weight transpose+convert: Wt[w][h][e] = bf16(W_w[e][h]) ----
__global__ __launch_bounds__(256) void k_cvt_w(const float* __restrict__ Wq,
                                               const float* __restrict__ Wk,
                                               const float* __restrict__ Wv,
                                               u16* __restrict__ Wt) {
  int t = blockIdx.x * 256 + threadIdx.x;  // 98304 threads
  int e0 = (t & 255) * 4;
  int h = (t >> 8) & 127;
  int w = t >> 15;
  const float* W = (w == 0) ? Wq : (w == 1) ? Wk : Wv;
  ushort4 o;
  o.x = f2bf(W[(size_t)(e0 + 0) * HD + h]);
  o.y = f2bf(W[(size_t)(e0 + 1) * HD + h]);
  o.z = f2bf(W[(size_t)(e0 + 2) * HD + h]);
  o.w = f2bf(W[(size_t)(e0 + 3) * HD + h]);
  *reinterpret_cast<ushort4*>(Wt + ((size_t)w * HD + h) * EMBD + e0) = o;
}

// ---------------- projections: Q,K row-major bf16; V written transposed ------
__global__ __launch_bounds__(256) void k_proj(const float* __restrict__ x,
                                              const u16* __restrict__ Wt,
                                              u16* __restrict__ Qb,
                                              u16* __restrict__ Kb,
                                              u16* __restrict__ Vtb) {
  __shared__ __align__(16) u16 As[128 * 64];
  __shared__ __align__(16) u16 Bs[128 * 64];
  const int mt = blockIdx.x;  // 0..127 -> rows mt*128 of [16384]
  const int w = blockIdx.y;   // 0=Q 1=K 2=V
  const int lane = threadIdx.x & 63, wave = threadIdx.x >> 6;
  const int wi = wave * 32;
  const u16* wp = Wt + (size_t)w * HD * EMBD;
  f32x4 zero = {0.f, 0.f, 0.f, 0.f};
  f32x4 acc[2][8];
#pragma unroll
  for (int a = 0; a < 2; a++)
#pragma unroll
    for (int b = 0; b < 8; b++) acc[a][b] = zero;

  for (int k0 = 0; k0 < EMBD; k0 += 64) {
    __syncthreads();
    stage_tile_f32<128, 64>(As, x + (size_t)mt * 128 * EMBD + k0, EMBD);
    stage_tile<128, 64>(Bs, wp + k0, EMBD);
    __syncthreads();
#pragma unroll
    for (int kk = 0; kk < 64; kk += 32) {
      bf16x8 af0 = frag_ld<128>(As, wi + (lane & 15), kk + (lane >> 4) * 8);
      bf16x8 af1 = frag_ld<128>(As, wi + 16 + (lane & 15), kk + (lane >> 4) * 8);
#pragma unroll
      for (int fh = 0; fh < 8; fh++) {
        bf16x8 bw = frag_ld<128>(Bs, fh * 16 + (lane & 15), kk + (lane >> 4) * 8);
        acc[0][fh] = mfma16(af0, bw, acc[0][fh]);
        acc[1][fh] = mfma16(af1, bw, acc[1][fh]);
      }
    }
  }
  const int bb = mt >> 4;
  if (w < 2) {
    u16* P = (w == 0) ? Qb : Kb;
#pragma unroll
    for (int fi = 0; fi < 2; fi++)
#pragma unroll
      for (int fh = 0; fh < 8; fh++)
#pragma unroll
        for (int r = 0; r < 4; r++) {
          int t_ = mt * 128 + wi + fi * 16 + (lane >> 4) * 4 + r;
          int h = fh * 16 + (lane & 15);
          P[(size_t)t_ * HD + h] = f2bf(acc[fi][fh][r]);
        }
  } else {
#pragma unroll
    for (int fi = 0; fi < 2; fi++)
#pragma unroll
      for (int fh = 0; fh < 8; fh++) {
        int h = fh * 16 + (lane & 15);
        int t0 = (mt & 15) * 128 + wi + fi * 16 + (lane >> 4) * 4;
        ushort4 o;
        o.x = f2bf(acc[fi][fh][0]);
        o.y = f2bf(acc[fi][fh][1]);
        o.z = f2bf(acc[fi][fh][2]);
        o.w = f2bf(acc[fi][fh][3]);
        *reinterpret_cast<ushort4*>(Vtb + ((size_t)bb * HD + h) * SEQ + t0) = o;
      }
  }
}

__device__ inline void merge_ml(float& m, float& l, float m2, float l2) {
  float mn = fmaxf(m, m2);
  float a = (m > -1e37f) ? l * __expf(m - mn) : 0.f;
  float b = (m2 > -1e37f) ? l2 * __expf(m2 - mn) : 0.f;
  m = mn;
  l = a + b;
}

// ---------------- stats pass: partial (m_j, l_j) over i-tile slices ----------
__global__ __launch_bounds__(256) void k_statsA(const u16* __restrict__ Qb,
                                                const u16* __restrict__ Kb,
                                                float* __restrict__ mpart,
                                                float* __restrict__ lpart) {
  __shared__ __align__(16) u16 Ks[128 * 128];
  __shared__ __align__(16) u16 Qs[128 * 128];
  const int jt = blockIdx.x >> 2, sl = blockIdx.x & 3, bb = blockIdx.y;
  const int lane = threadIdx.x & 63, wave = threadIdx.x >> 6, wj = wave * 32;
  stage_tile<128, 128>(Ks, Kb + ((size_t)bb * SEQ + jt * 128) * HD, HD);
  float m[2][4], l[2][4];
#pragma unroll
  for (int a = 0; a < 2; a++)
#pragma unroll
    for (int r = 0; r < 4; r++) {
      m[a][r] = -INFINITY;
      l[a][r] = 0.f;
    }
  f32x4 zero = {0.f, 0.f, 0.f, 0.f};
  int it0 = jt + ((sl - jt) & 3);
  for (int it = it0; it < 16; it += 4) {
    __syncthreads();
    stage_tile<128, 128>(Qs, Qb + ((size_t)bb * SEQ + it * 128) * HD, HD);
    __syncthreads();
    f32x4 acc[2][8];
#pragma unroll
    for (int a = 0; a < 2; a++)
#pragma unroll
      for (int b = 0; b < 8; b++) acc[a][b] = zero;
#pragma unroll
    for (int kk = 0; kk < 128; kk += 32) {
      bf16x8 af0 = frag_ld<256>(Ks, wj + (lane & 15), kk + (lane >> 4) * 8);
      bf16x8 af1 = frag_ld<256>(Ks, wj + 16 + (lane & 15), kk + (lane >> 4) * 8);
#pragma unroll
      for (int fi = 0; fi < 8; fi++) {
        bf16x8 bq = frag_ld<256>(Qs, fi * 16 + (lane & 15), kk + (lane >> 4) * 8);
        acc[0][fi] = mfma16(af0, bq, acc[0][fi]);
        acc[1][fi] = mfma16(af1, bq, acc[1][fi]);
      }
    }
#pragma unroll
    for (int fj = 0; fj < 2; fj++)
#pragma unroll
      for (int r = 0; r < 4; r++) {
        int jg = jt * 128 + wj + fj * 16 + (lane >> 4) * 4 + r;
        float v[8];
        float vmax = -INFINITY;
#pragma unroll
        for (int fi = 0; fi < 8; fi++) {
          int ig = it * 128 + fi * 16 + (lane & 15);
          v[fi] = (ig >= jg) ? acc[fj][fi][r] : -INFINITY;
          vmax = fmaxf(vmax, v[fi]);
        }
        if (vmax > -1e37f) {
          float mn = fmaxf(m[fj][r], vmax);
          float sc = (m[fj][r] > -1e37f) ? __expf(m[fj][r] - mn) : 0.f;
          float ss = 0.f;
#pragma unroll
          for (int fi = 0; fi < 8; fi++)
            ss += (v[fi] > -1e37f) ? __expf(v[fi] - mn) : 0.f;
          l[fj][r] = l[fj][r] * sc + ss;
          m[fj][r] = mn;
        }
      }
  }
  // merge across the 16 lanes of each group (same j, different i subsets)
#pragma unroll
  for (int fj = 0; fj < 2; fj++)
#pragma unroll
    for (int r = 0; r < 4; r++)
      for (int msk = 1; msk <= 8; msk <<= 1) {
        float m2 = __shfl_xor(m[fj][r], msk);
        float l2 = __shfl_xor(l[fj][r], msk);
        merge_ml(m[fj][r], l[fj][r], m2, l2);
      }
  if ((lane & 15) == 0) {
#pragma unroll
    for (int fj = 0; fj < 2; fj++)
#pragma unroll
      for (int r = 0; r < 4; r++) {
        int j = jt * 128 + wj + fj * 16 + (lane >> 4) * 4 + r;
        size_t idx = (size_t)sl * (NB * SEQ) + (size_t)bb * SEQ + j;
        mpart[idx] = m[fj][r];
        lpart[idx] = l[fj][r];
      }
  }
}

__global__ __launch_bounds__(256) void k_stats_reduce(const float* __restrict__ mpart,
                                                      const float* __restrict__ lpart,
                                                      float* __restrict__ Mg,
                                                      float* __restrict__ RLg) {
  int idx = blockIdx.x * 256 + threadIdx.x;  // < 16384
  float m = -INFINITY;
#pragma unroll
  for (int sl = 0; sl < 4; sl++) m = fmaxf(m, mpart[sl * (NB * SEQ) + idx]);
  float l = 0.f;
#pragma unroll
  for (int sl = 0; sl < 4; sl++) {
    float ms = mpart[sl * (NB * SEQ) + idx];
    if (ms > -1e37f) l += lpart[sl * (NB * SEQ) + idx] * __expf(ms - m);
  }
  Mg[idx] = m;
  RLg[idx] = 1.0f / l;
}

// ---------------- PV pass: recompute S, P = exp(S-m_j)/l_j, out += P V ------
__global__ __launch_bounds__(256) void k_passB(const u16* __restrict__ Qb,
                                               const u16* __restrict__ Kb,
                                               const u16* __restrict__ Vtb,
                                               const float* __restrict__ Mg,
                                               const float* __restrict__ RLg,
                                               float* __restrict__ opart) {
  __shared__ __align__(16) u16 Qs[128 * 128];  // first 16KB reused as Ps
  __shared__ __align__(16) u16 Ks[64 * 128];
  __shared__ __align__(16) u16 Vs[128 * 64];
  __shared__ float sm[64];
  __shared__ float srl[64];
  u16* Ps = Qs;
  const int it = blockIdx.x >> 2, sl = blockIdx.x & 3, bb = blockIdx.y;
  const int lane = threadIdx.x & 63, wave = threadIdx.x >> 6, wi = wave * 32;
  stage_tile<128, 128>(Qs, Qb + ((size_t)bb * SEQ + it * 128) * HD, HD);
  __syncthreads();
  bf16x8 qf[2][4];
#pragma unroll
  for (int fi = 0; fi < 2; fi++)
#pragma unroll
    for (int kk = 0; kk < 4; kk++)
      qf[fi][kk] = frag_ld<256>(Qs, wi + fi * 16 + (lane & 15), kk * 32 + (lane >> 4) * 8);
  f32x4 zero = {0.f, 0.f, 0.f, 0.f};
  f32x4 accO[2][8];
#pragma unroll
  for (int a = 0; a < 2; a++)
#pragma unroll
    for (int b = 0; b < 8; b++) accO[a][b] = zero;

  for (int jt = sl; jt <= 2 * it + 1; jt += 4) {
    __syncthreads();  // prior PV reads / Q-frag reads done before Ps,Ks,Vs reuse
    stage_tile<64, 128>(Ks, Kb + ((size_t)bb * SEQ + jt * 64) * HD, HD);
    stage_tile<128, 64>(Vs, Vtb + (size_t)bb * HD * SEQ + jt * 64, SEQ);
    if (threadIdx.x < 64)
      sm[threadIdx.x] = Mg[bb * SEQ + jt * 64 + threadIdx.x];
    else if (threadIdx.x < 128)
      srl[threadIdx.x - 64] = RLg[bb * SEQ + jt * 64 + threadIdx.x - 64];
    __syncthreads();
    f32x4 accS[2][4];
#pragma unroll
    for (int a = 0; a < 2; a++)
#pragma unroll
      for (int b = 0; b < 4; b++) accS[a][b] = zero;
#pragma unroll
    for (int kk = 0; kk < 4; kk++) {
#pragma unroll
      for (int fj = 0; fj < 4; fj++) {
        bf16x8 bk = frag_ld<256>(Ks, fj * 16 + (lane & 15), kk * 32 + (lane >> 4) * 8);
        accS[0][fj] = mfma16(qf[0][kk], bk, accS[0][fj]);
        accS[1][fj] = mfma16(qf[1][kk], bk, accS[1][fj]);
      }
    }
    // P = exp(S - m_j) / l_j, causal-masked; write to LDS (wave-private rows)
#pragma unroll
    for (int fi = 0; fi < 2; fi++)
#pragma unroll
      for (int fj = 0; fj < 4; fj++) {
        int jloc = fj * 16 + (lane & 15);
        float mj = sm[jloc], rlj = srl[jloc];
        int jg = jt * 64 + jloc;
#pragma unroll
        for (int r = 0; r < 4; r++) {
          int iloc = wi + fi * 16 + (lane >> 4) * 4 + r;
          int ig = it * 128 + iloc;
          float p = __expf(accS[fi][fj][r] - mj) * rlj;
          if (ig < jg) p = 0.f;
          int byte = iloc * 128 + jloc * 2;
          byte ^= (iloc & 7) << 4;
          *reinterpret_cast<u16*>(reinterpret_cast<char*>(Ps) + byte) = f2bf(p);
        }
      }
    __syncthreads();
#pragma unroll
    for (int kk = 0; kk < 2; kk++) {
      bf16x8 pa0 = frag_ld<128>(Ps, wi + (lane & 15), kk * 32 + (lane >> 4) * 8);
      bf16x8 pa1 = frag_ld<128>(Ps, wi + 16 + (lane & 15), kk * 32 + (lane >> 4) * 8);
#pragma unroll
      for (int fh = 0; fh < 8; fh++) {
        bf16x8 bv = frag_ld<128>(Vs, fh * 16 + (lane & 15), kk * 32 + (lane >> 4) * 8);
        accO[0][fh] = mfma16(pa0, bv, accO[0][fh]);
        accO[1][fh] = mfma16(pa1, bv, accO[1][fh]);
      }
    }
  }
#pragma unroll
  for (int fi = 0; fi < 2; fi++)
#pragma unroll
    for (int fh = 0; fh < 8; fh++)
#pragma unroll
      for (int r = 0; r < 4; r++) {
        int ig = it * 128 + wi + fi * 16 + (lane >> 4) * 4 + r;
        int h = fh * 16 + (lane & 15);
        opart[(((size_t)sl * NB + bb) * SEQ + ig) * HD + h] = accO[fi][fh][r];
      }
}

__global__ __launch_bounds__(256) void k_reduceB(const float* __restrict__ opart,
                                                 float* __restrict__ out) {
  size_t i = ((size_t)blockIdx.x * 256 + threadIdx.x) * 4;
  const size_t S = (size_t)NB * SEQ * HD;
  float4 a = *reinterpret_cast<const float4*>(opart + i);
  float4 b = *reinterpret_cast<const float4*>(opart + S + i);
  float4 c = *reinterpret_cast<const float4*>(opart + 2 * S + i);
  float4 d = *reinterpret_cast<const float4*>(opart + 3 * S + i);
  float4 o;
  o.x = a.x + b.x + c.x + d.x;
  o.y = a.y + b.y + c.y + d.y;
  o.z = a.z + b.z + c.z + d.z;
  o.w = a.w + b.w + c.w + d.w;
  *reinterpret_cast<float4*>(out + i) = o;
}

extern "C" void kernel_launch(void* const* d_in, const int* in_sizes, int n_in,
                              void* d_out, int out_size, void* d_ws, size_t ws_size,
                              hipStream_t stream) {
  (void)in_sizes; (void)n_in; (void)out_size; (void)ws_size;
  const float* x = (const float*)d_in[0];
  const float* Wk = (const float*)d_in[1];
  const float* Wq = (const float*)d_in[2];
  const float* Wv = (const float*)d_in[3];
  float* out = (float*)d_out;
  char* ws = (char*)d_ws;

  u16* Wt = (u16*)(ws + 0);              //   786,432 B
  u16* Qb = (u16*)(ws + 786432);         // 4,194,304 B
  u16* Kb = (u16*)(ws + 4980736);        // 4,194,304 B
  u16* Vtb = (u16*)(ws + 9175040);       // 4,194,304 B
  float* mpart = (float*)(ws + 13369344);   // 262,144 B
  float* lpart = (float*)(ws + 13631488);   // 262,144 B
  float* Mg = (float*)(ws + 13893632);      //  65,536 B
  float* RLg = (float*)(ws + 13959168);     //  65,536 B
  float* opart = (float*)(ws + 14024704);   // 33,554,432 B  (total ~45.4 MB)

  k_cvt_w<<<384, 256, 0, stream>>>(Wq, Wk, Wv, Wt);
  k_proj<<<dim3(128, 3), 256, 0, stream>>>(x, Wt, Qb, Kb, Vtb);
  k_statsA<<<dim3(64, 8), 256, 0, stream>>>(Qb, Kb, mpart, lpart);
  k_stats_reduce<<<64, 256, 0, stream>>>(mpart, lpart, Mg, RLg);
  k_passB<<<dim3(64, 8), 256, 0, stream>>>(Qb, Kb, Vtb, Mg, RLg, opart);
  k_reduceB<<<2048, 256, 0, stream>>>(opart, out);
}

// Round 2
// 95.255 us; speedup vs baseline: 1.3598x; 1.3598x over previous
//
#include <hip/hip_runtime.h>

typedef unsigned short u16;
typedef unsigned int u32;
typedef _Float16 f16;
typedef __attribute__((ext_vector_type(8))) _Float16 f16x8;
typedef __attribute__((ext_vector_type(4))) float f32x4;

constexpr int SEQ = 2048;
constexpr int EMBD = 1024;
constexpr int HD = 128;
constexpr int NB = 8;
constexpr int NSL = 8;  // j/i slices for balance

__device__ inline u16 f2h(float f) {
  f16 h = (f16)f;
  return __builtin_bit_cast(u16, h);
}
__device__ inline u32 pack2(float a, float b) {
  return (u32)f2h(a) | ((u32)f2h(b) << 16);
}

__device__ inline f32x4 mfma16(f16x8 a, f16x8 b, f32x4 c) {
  return __builtin_amdgcn_mfma_f32_16x16x32_f16(a, b, c, 0, 0, 0);
}

// Stage a row-major [R][C] fp16 tile into LDS with XOR swizzle (byte ^= (row&7)<<4).
template<int R, int C>
__device__ inline void stage_tile(u16* lds, const u16* __restrict__ g, int ldg) {
  constexpr int CH = (R * C) / (8 * 256);
  int t = threadIdx.x;
#pragma unroll
  for (int ch = 0; ch < CH; ++ch) {
    int lin = ch * 256 + t;
    int row = lin / (C / 8);
    int cc = lin % (C / 8);
    int byte = row * (C * 2) + cc * 16;
    byte ^= (row & 7) << 4;
    *reinterpret_cast<uint4*>(reinterpret_cast<char*>(lds) + byte) =
        *reinterpret_cast<const uint4*>(g + (size_t)row * ldg + cc * 8);
  }
}

// Same, but source is fp32 (converted to fp16 on the fly).
template<int R, int C>
__device__ inline void stage_tile_f32(u16* lds, const float* __restrict__ g, int ldg) {
  constexpr int CH = (R * C) / (8 * 256);
  int t = threadIdx.x;
#pragma unroll
  for (int ch = 0; ch < CH; ++ch) {
    int lin = ch * 256 + t;
    int row = lin / (C / 8);
    int cc = lin % (C / 8);
    const float* p = g + (size_t)row * ldg + cc * 8;
    float4 a = *reinterpret_cast<const float4*>(p);
    float4 b = *reinterpret_cast<const float4*>(p + 4);
    uint4 o;
    o.x = pack2(a.x, a.y);
    o.y = pack2(a.z, a.w);
    o.z = pack2(b.x, b.y);
    o.w = pack2(b.z, b.w);
    int byte = row * (C * 2) + cc * 16;
    byte ^= (row & 7) << 4;
    *reinterpret_cast<uint4*>(reinterpret_cast<char*>(lds) + byte) = o;
  }
}

// Read one 8-element (16B) MFMA operand fragment from a swizzled LDS tile.
template<int RB>
__device__ inline f16x8 frag_ld(const u16* lds, int row, int elem) {
  int byte = row * RB + elem * 2;
  byte ^= (row & 7) << 4;
  return *reinterpret_cast<const f16x8*>(reinterpret_cast<const char*>(lds) + byte);
}

// ---------------- weight transpose+convert: Wt[w][h][e] = f16(W_w[e][h]) ----
__global__ __launch_bounds__(256) void k_cvt_w(const float* __restrict__ Wq,
                                               const float* __restrict__ Wk,
                                               const float* __restrict__ Wv,
                                               u16* __restrict__ Wt) {
  int t = blockIdx.x * 256 + threadIdx.x;  // 98304 threads
  int e0 = (t & 255) * 4;
  int h = (t >> 8) & 127;
  int w = t >> 15;
  const float* W = (w == 0) ? Wq : (w == 1) ? Wk : Wv;
  ushort4 o;
  o.x = f2h(W[(size_t)(e0 + 0) * HD + h]);
  o.y = f2h(W[(size_t)(e0 + 1) * HD + h]);
  o.z = f2h(W[(size_t)(e0 + 2) * HD + h]);
  o.w = f2h(W[(size_t)(e0 + 3) * HD + h]);
  *reinterpret_cast<ushort4*>(Wt + ((size_t)w * HD + h) * EMBD + e0) = o;
}

// ---------------- fused projections: Q,K row-major fp16; V transposed --------
// 512 blocks, 32 rows each; x read exactly once from HBM.
__global__ __launch_bounds__(256, 2) void k_proj(const float* __restrict__ x,
                                                 const u16* __restrict__ Wt,
                                                 u16* __restrict__ Qb,
                                                 u16* __restrict__ Kb,
                                                 u16* __restrict__ Vtb) {
  __shared__ __align__(16) u16 As[32 * 64];
  __shared__ __align__(16) u16 Bs[3][128 * 64];
  const int mt = blockIdx.x;  // rows mt*32
  const int lane = threadIdx.x & 63, wave = threadIdx.x >> 6;
  const int rh = wave & 1, fq = wave >> 1;  // row half, fh quarter
  f32x4 zero = {0.f, 0.f, 0.f, 0.f};
  f32x4 acc[3][4];
#pragma unroll
  for (int w = 0; w < 3; w++)
#pragma unroll
    for (int f = 0; f < 4; f++) acc[w][f] = zero;

  for (int k0 = 0; k0 < EMBD; k0 += 64) {
    __syncthreads();
    stage_tile_f32<32, 64>(As, x + (size_t)mt * 32 * EMBD + k0, EMBD);
    stage_tile<128, 64>(Bs[0], Wt + 0 * HD * EMBD + k0, EMBD);
    stage_tile<128, 64>(Bs[1], Wt + 1 * (size_t)HD * EMBD + k0, EMBD);
    stage_tile<128, 64>(Bs[2], Wt + 2 * (size_t)HD * EMBD + k0, EMBD);
    __syncthreads();
#pragma unroll
    for (int kk = 0; kk < 2; kk++) {
      f16x8 af = frag_ld<128>(As, rh * 16 + (lane & 15), kk * 32 + (lane >> 4) * 8);
#pragma unroll
      for (int w = 0; w < 3; w++)
#pragma unroll
        for (int f = 0; f < 4; f++) {
          f16x8 bw = frag_ld<128>(Bs[w], (fq * 4 + f) * 16 + (lane & 15),
                                  kk * 32 + (lane >> 4) * 8);
          acc[w][f] = mfma16(af, bw, acc[w][f]);
        }
    }
  }
  // Q, K row-major
#pragma unroll
  for (int w = 0; w < 2; w++) {
    u16* P = w ? Kb : Qb;
#pragma unroll
    for (int f = 0; f < 4; f++)
#pragma unroll
      for (int r = 0; r < 4; r++) {
        int i = mt * 32 + rh * 16 + (lane >> 4) * 4 + r;
        int h = (fq * 4 + f) * 16 + (lane & 15);
        P[(size_t)i * HD + h] = f2h(acc[w][f][r]);
      }
  }
  // V transposed: Vt[bb][h][t]
  {
    int bb = (mt * 32) >> 11;
    int t0 = (mt * 32) & 2047;
#pragma unroll
    for (int f = 0; f < 4; f++) {
      int h = (fq * 4 + f) * 16 + (lane & 15);
      int t = t0 + rh * 16 + (lane >> 4) * 4;
      ushort4 o;
      o.x = f2h(acc[2][f][0]);
      o.y = f2h(acc[2][f][1]);
      o.z = f2h(acc[2][f][2]);
      o.w = f2h(acc[2][f][3]);
      *reinterpret_cast<ushort4*>(Vtb + ((size_t)bb * HD + h) * SEQ + t) = o;
    }
  }
}

__device__ inline void merge_ml(float& m, float& l, float m2, float l2) {
  float mn = fmaxf(m, m2);
  float a = (m > -1e37f) ? l * __expf(m - mn) : 0.f;
  float b = (m2 > -1e37f) ? l2 * __expf(m2 - mn) : 0.f;
  m = mn;
  l = a + b;
}

// ---------------- stats pass: partial (m_j, l_j); paired j-tiles, 8 i-slices -
__global__ __launch_bounds__(256, 2) void k_statsA(const u16* __restrict__ Qb,
                                                   const u16* __restrict__ Kb,
                                                   float* __restrict__ mpart,
                                                   float* __restrict__ lpart) {
  __shared__ __align__(16) u16 Tile[128 * 128];
  const int id = blockIdx.y * 64 + blockIdx.x;
  const int bb = id & 7;          // XCD-affine: same-batch blocks share an XCD L2
  const int z = (id >> 3) & 7, sl = id >> 6;
  const int lane = threadIdx.x & 63, wave = threadIdx.x >> 6, wj = wave * 32;
  f32x4 zero = {0.f, 0.f, 0.f, 0.f};

  for (int ph = 0; ph < 2; ph++) {
    const int jt = ph ? (15 - z) : z;
    __syncthreads();
    stage_tile<128, 128>(Tile, Kb + ((size_t)bb * SEQ + jt * 128) * HD, HD);
    __syncthreads();
    f16x8 af[2][4];
#pragma unroll
    for (int fj = 0; fj < 2; fj++)
#pragma unroll
      for (int kk = 0; kk < 4; kk++)
        af[fj][kk] = frag_ld<256>(Tile, wj + fj * 16 + (lane & 15), kk * 32 + (lane >> 4) * 8);
    float m[2][4], l[2][4];
#pragma unroll
    for (int a = 0; a < 2; a++)
#pragma unroll
      for (int r = 0; r < 4; r++) {
        m[a][r] = -INFINITY;
        l[a][r] = 0.f;
      }
    int it0 = jt + ((sl - jt) & 7);
    for (int it = it0; it < 16; it += 8) {
      __syncthreads();
      stage_tile<128, 128>(Tile, Qb + ((size_t)bb * SEQ + it * 128) * HD, HD);
      __syncthreads();
      f32x4 acc[2][8];
#pragma unroll
      for (int a = 0; a < 2; a++)
#pragma unroll
        for (int b = 0; b < 8; b++) acc[a][b] = zero;
#pragma unroll
      for (int kk = 0; kk < 4; kk++)
#pragma unroll
        for (int fi = 0; fi < 8; fi++) {
          f16x8 bq = frag_ld<256>(Tile, fi * 16 + (lane & 15), kk * 32 + (lane >> 4) * 8);
          acc[0][fi] = mfma16(af[0][kk], bq, acc[0][fi]);
          acc[1][fi] = mfma16(af[1][kk], bq, acc[1][fi]);
        }
#pragma unroll
      for (int fj = 0; fj < 2; fj++)
#pragma unroll
        for (int r = 0; r < 4; r++) {
          int jg = jt * 128 + wj + fj * 16 + (lane >> 4) * 4 + r;
          float v[8];
          float vmax = -INFINITY;
#pragma unroll
          for (int fi = 0; fi < 8; fi++) {
            int ig = it * 128 + fi * 16 + (lane & 15);
            v[fi] = (ig >= jg) ? acc[fj][fi][r] : -INFINITY;
            vmax = fmaxf(vmax, v[fi]);
          }
          if (vmax > -1e37f) {
            float mn = fmaxf(m[fj][r], vmax);
            float sc = (m[fj][r] > -1e37f) ? __expf(m[fj][r] - mn) : 0.f;
            float ss = 0.f;
#pragma unroll
            for (int fi = 0; fi < 8; fi++)
              ss += (v[fi] > -1e37f) ? __expf(v[fi] - mn) : 0.f;
            l[fj][r] = l[fj][r] * sc + ss;
            m[fj][r] = mn;
          }
        }
    }
#pragma unroll
    for (int fj = 0; fj < 2; fj++)
#pragma unroll
      for (int r = 0; r < 4; r++)
        for (int msk = 1; msk <= 8; msk <<= 1) {
          float m2 = __shfl_xor(m[fj][r], msk);
          float l2 = __shfl_xor(l[fj][r], msk);
          merge_ml(m[fj][r], l[fj][r], m2, l2);
        }
    if ((lane & 15) == 0) {
#pragma unroll
      for (int fj = 0; fj < 2; fj++)
#pragma unroll
        for (int r = 0; r < 4; r++) {
          int j = jt * 128 + wj + fj * 16 + (lane >> 4) * 4 + r;
          size_t idx = (size_t)sl * (NB * SEQ) + (size_t)bb * SEQ + j;
          mpart[idx] = m[fj][r];
          lpart[idx] = l[fj][r];
        }
    }
  }
}

__global__ __launch_bounds__(256) void k_stats_reduce(const float* __restrict__ mpart,
                                                      const float* __restrict__ lpart,
                                                      float* __restrict__ Mg,
                                                      float* __restrict__ RLg) {
  int idx = blockIdx.x * 256 + threadIdx.x;  // < 16384
  float m = -INFINITY;
#pragma unroll
  for (int sl = 0; sl < NSL; sl++) m = fmaxf(m, mpart[sl * (NB * SEQ) + idx]);
  float l = 0.f;
#pragma unroll
  for (int sl = 0; sl < NSL; sl++) {
    float ms = mpart[sl * (NB * SEQ) + idx];
    if (ms > -1e37f) l += lpart[sl * (NB * SEQ) + idx] * __expf(ms - m);
  }
  Mg[idx] = m;
  RLg[idx] = 1.0f / l;
}

// ---------------- PV pass: paired i-tiles, 8 j-slices, Q frags from global ---
__global__ __launch_bounds__(256, 2) void k_passB(const u16* __restrict__ Qb,
                                                  const u16* __restrict__ Kb,
                                                  const u16* __restrict__ Vtb,
                                                  const float* __restrict__ Mg,
                                                  const float* __restrict__ RLg,
                                                  u16* __restrict__ opart) {
  __shared__ __align__(16) u16 Ks[64 * 128];
  __shared__ __align__(16) u16 Vs[128 * 64];
  __shared__ __align__(16) u16 Ps[128 * 64];
  __shared__ float sm[64];
  __shared__ float srl[64];
  const int id = blockIdx.y * 64 + blockIdx.x;
  const int bb = id & 7;  // XCD-affine batch
  const int z = (id >> 3) & 7, sl = id >> 6;
  const int lane = threadIdx.x & 63, wave = threadIdx.x >> 6, wi = wave * 32;
  f32x4 zero = {0.f, 0.f, 0.f, 0.f};

  for (int ph = 0; ph < 2; ph++) {
    const int it = ph ? (15 - z) : z;
    f16x8 qf[2][4];
#pragma unroll
    for (int fi = 0; fi < 2; fi++)
#pragma unroll
      for (int kk = 0; kk < 4; kk++) {
        size_t row = (size_t)bb * SEQ + it * 128 + wi + fi * 16 + (lane & 15);
        qf[fi][kk] = *reinterpret_cast<const f16x8*>(Qb + row * HD + kk * 32 + (lane >> 4) * 8);
      }
    f32x4 accO[2][8];
#pragma unroll
    for (int a = 0; a < 2; a++)
#pragma unroll
      for (int b = 0; b < 8; b++) accO[a][b] = zero;

    for (int jt = sl; jt <= 2 * it + 1; jt += 8) {
      __syncthreads();
      stage_tile<64, 128>(Ks, Kb + ((size_t)bb * SEQ + jt * 64) * HD, HD);
      stage_tile<128, 64>(Vs, Vtb + (size_t)bb * HD * SEQ + jt * 64, SEQ);
      if (threadIdx.x < 64)
        sm[threadIdx.x] = Mg[bb * SEQ + jt * 64 + threadIdx.x];
      else if (threadIdx.x < 128)
        srl[threadIdx.x - 64] = RLg[bb * SEQ + jt * 64 + threadIdx.x - 64];
      __syncthreads();
      f32x4 accS[2][4];
#pragma unroll
      for (int a = 0; a < 2; a++)
#pragma unroll
        for (int b = 0; b < 4; b++) accS[a][b] = zero;
#pragma unroll
      for (int kk = 0; kk < 4; kk++)
#pragma unroll
        for (int fj = 0; fj < 4; fj++) {
          f16x8 bk = frag_ld<256>(Ks, fj * 16 + (lane & 15), kk * 32 + (lane >> 4) * 8);
          accS[0][fj] = mfma16(qf[0][kk], bk, accS[0][fj]);
          accS[1][fj] = mfma16(qf[1][kk], bk, accS[1][fj]);
        }
      // P = exp(S - m_j) * (1/l_j), causal-masked; wave-private rows of Ps
#pragma unroll
      for (int fi = 0; fi < 2; fi++)
#pragma unroll
        for (int fj = 0; fj < 4; fj++) {
          int jloc = fj * 16 + (lane & 15);
          float mj = sm[jloc], rlj = srl[jloc];
          int jg = jt * 64 + jloc;
#pragma unroll
          for (int r = 0; r < 4; r++) {
            int iloc = wi + fi * 16 + (lane >> 4) * 4 + r;
            int ig = it * 128 + iloc;
            float p = __expf(accS[fi][fj][r] - mj) * rlj;
            if (ig < jg) p = 0.f;
            int byte = iloc * 128 + jloc * 2;
            byte ^= (iloc & 7) << 4;
            *reinterpret_cast<u16*>(reinterpret_cast<char*>(Ps) + byte) = f2h(p);
          }
        }
      __syncthreads();
#pragma unroll
      for (int kk = 0; kk < 2; kk++) {
        f16x8 pa0 = frag_ld<128>(Ps, wi + (lane & 15), kk * 32 + (lane >> 4) * 8);
        f16x8 pa1 = frag_ld<128>(Ps, wi + 16 + (lane & 15), kk * 32 + (lane >> 4) * 8);
#pragma unroll
        for (int fh = 0; fh < 8; fh++) {
          f16x8 bv = frag_ld<128>(Vs, fh * 16 + (lane & 15), kk * 32 + (lane >> 4) * 8);
          accO[0][fh] = mfma16(pa0, bv, accO[0][fh]);
          accO[1][fh] = mfma16(pa1, bv, accO[1][fh]);
        }
      }
    }
#pragma unroll
    for (int fi = 0; fi < 2; fi++)
#pragma unroll
      for (int fh = 0; fh < 8; fh++)
#pragma unroll
        for (int r = 0; r < 4; r++) {
          int ig = it * 128 + wi + fi * 16 + (lane >> 4) * 4 + r;
          int h = fh * 16 + (lane & 15);
          opart[(((size_t)sl * NB + bb) * SEQ + ig) * HD + h] = f2h(accO[fi][fh][r]);
        }
  }
}

__global__ __launch_bounds__(256) void k_reduceB(const u16* __restrict__ opart,
                                                 float* __restrict__ out) {
  size_t base = ((size_t)blockIdx.x * 256 + threadIdx.x) * 8;
  const size_t S = (size_t)NB * SEQ * HD;
  float s[8];
#pragma unroll
  for (int j = 0; j < 8; j++) s[j] = 0.f;
#pragma unroll
  for (int sl = 0; sl < NSL; sl++) {
    f16x8 v = *reinterpret_cast<const f16x8*>(opart + sl * S + base);
#pragma unroll
    for (int j = 0; j < 8; j++) s[j] += (float)v[j];
  }
  float4 o0 = {s[0], s[1], s[2], s[3]};
  float4 o1 = {s[4], s[5], s[6], s[7]};
  *reinterpret_cast<float4*>(out + base) = o0;
  *reinterpret_cast<float4*>(out + base + 4) = o1;
}

extern "C" void kernel_launch(void* const* d_in, const int* in_sizes, int n_in,
                              void* d_out, int out_size, void* d_ws, size_t ws_size,
                              hipStream_t stream) {
  (void)in_sizes; (void)n_in; (void)out_size; (void)ws_size;
  const float* x = (const float*)d_in[0];
  const float* Wk = (const float*)d_in[1];
  const float* Wq = (const float*)d_in[2];
  const float* Wv = (const float*)d_in[3];
  float* out = (float*)d_out;
  char* ws = (char*)d_ws;

  u16* Wt = (u16*)(ws + 0);                //   786,432 B
  u16* Qb = (u16*)(ws + 786432);           // 4,194,304 B
  u16* Kb = (u16*)(ws + 4980736);          // 4,194,304 B
  u16* Vtb = (u16*)(ws + 9175040);         // 4,194,304 B
  float* mpart = (float*)(ws + 13369344);  //   524,288 B
  float* lpart = (float*)(ws + 13893632);  //   524,288 B
  float* Mg = (float*)(ws + 14417920);     //    65,536 B
  float* RLg = (float*)(ws + 14483456);    //    65,536 B
  u16* opart = (u16*)(ws + 14548992);      // 33,554,432 B (total ~45.9 MB)

  k_cvt_w<<<384, 256, 0, stream>>>(Wq, Wk, Wv, Wt);
  k_proj<<<512, 256, 0, stream>>>(x, Wt, Qb, Kb, Vtb);
  k_statsA<<<dim3(64, 8), 256, 0, stream>>>(Qb, Kb, mpart, lpart);
  k_stats_reduce<<<64, 256, 0, stream>>>(mpart, lpart, Mg, RLg);
  k_passB<<<dim3(64, 8), 256, 0, stream>>>(Qb, Kb, Vtb, Mg, RLg, opart);
  k_reduceB<<<1024, 256, 0, stream>>>(opart, out);
}

// Round 3
// 84.668 us; speedup vs baseline: 1.5298x; 1.1250x over previous
//
#include <hip/hip_runtime.h>

typedef unsigned short u16;
typedef unsigned int u32;
typedef _Float16 f16;
typedef __attribute__((ext_vector_type(8))) _Float16 f16x8;
typedef __attribute__((ext_vector_type(4))) float f32x4;

constexpr int SEQ = 2048;
constexpr int EMBD = 1024;
constexpr int HD = 128;
constexpr int NB = 8;
constexpr int NSL = 8;

__device__ inline u16 f2h(float f) { return __builtin_bit_cast(u16, (f16)f); }
__device__ inline u32 pack2(float a, float b) { return (u32)f2h(a) | ((u32)f2h(b) << 16); }

__device__ inline f32x4 mfma16(f16x8 a, f16x8 b, f32x4 c) {
  return __builtin_amdgcn_mfma_f32_16x16x32_f16(a, b, c, 0, 0, 0);
}

// 16B global -> LDS direct (no VGPR round trip)
__device__ __forceinline__ void gload16(const u16* g, u16* l) {
  __builtin_amdgcn_global_load_lds(
      (const __attribute__((address_space(1))) u32*)g,
      (__attribute__((address_space(3))) u32*)l, 16, 0, 0);
}

// Swizzled fragment read: tiles are stored (in LDS *and* in global scratch)
// row-major with within-row chunk XOR: byte ^= (row&7)<<4  (element ^= (row&7)<<3).
template<int RB>
__device__ inline f16x8 frag_ld(const u16* lds, int row, int e) {
  int byte = row * RB + ((e * 2) ^ ((row & 7) << 4));
  return *reinterpret_cast<const f16x8*>(reinterpret_cast<const char*>(lds) + byte);
}

// --------- weights: Wt[k0t][H][e] pre-swizzled tiles, H = w*128+h, 48KB/tile --
__global__ __launch_bounds__(256) void k_cvt_w(const float* __restrict__ Wq,
                                               const float* __restrict__ Wk,
                                               const float* __restrict__ Wv,
                                               u16* __restrict__ Wt) {
  int t = blockIdx.x * 256 + threadIdx.x;  // 98304
  int e0 = (t & 255) * 4;
  int H = t >> 8;  // 0..383
  int w = H >> 7, h = H & 127;
  const float* W = (w == 0) ? Wq : (w == 1) ? Wk : Wv;
  ushort4 o;
  o.x = f2h(W[(size_t)(e0 + 0) * HD + h]);
  o.y = f2h(W[(size_t)(e0 + 1) * HD + h]);
  o.z = f2h(W[(size_t)(e0 + 2) * HD + h]);
  o.w = f2h(W[(size_t)(e0 + 3) * HD + h]);
  int k0t = e0 >> 6, ec = e0 & 63;
  size_t el = (size_t)(k0t * 384 + H) * 64 + (ec ^ ((H & 7) << 3));
  *reinterpret_cast<ushort4*>(Wt + el) = o;
}

// --------- fused projections: 64 rows x 192 cols per block, 2-phase dbuf -----
// Q,K written pre-swizzled row-major; V written pre-swizzled transposed tiles.
__global__ __launch_bounds__(512, 4) void k_proj(const float* __restrict__ x,
                                                 const u16* __restrict__ Wt,
                                                 u16* __restrict__ Qb,
                                                 u16* __restrict__ Kb,
                                                 u16* __restrict__ Vtb) {
  __shared__ __align__(16) u16 As[2][64 * 64];    // 16KB
  __shared__ __align__(16) u16 Bs[2][192 * 64];   // 48KB
  const int mt = blockIdx.x, ny = blockIdx.y;
  const int t = threadIdx.x, lane = t & 63, wave = t >> 6;
  const int rh = (wave & 1) * 32, cq = (wave >> 1) * 48;
  const int ar = t >> 3, ac = t & 7;
  const float* asrc = x + (size_t)(mt * 64 + ar) * EMBD + ac * 8;
  const int adst = ar * 64 + ((ac * 8) ^ ((ar & 7) << 3));
  f32x4 zero = {0.f, 0.f, 0.f, 0.f};
  f32x4 acc[2][3];
#pragma unroll
  for (int a = 0; a < 2; ++a)
#pragma unroll
    for (int b = 0; b < 3; ++b) acc[a][b] = zero;

  // prologue: stage k-step 0
  {
#pragma unroll
    for (int q = 0; q < 3; ++q) {
      int lin = q * 512 + t;
      gload16(Wt + ny * 12288 + lin * 8, &Bs[0][lin * 8]);
    }
    float4 a0 = *reinterpret_cast<const float4*>(asrc);
    float4 a1 = *reinterpret_cast<const float4*>(asrc + 4);
    uint4 o = {pack2(a0.x, a0.y), pack2(a0.z, a0.w), pack2(a1.x, a1.y), pack2(a1.z, a1.w)};
    *reinterpret_cast<uint4*>(&As[0][adst]) = o;
  }
  __syncthreads();
  int cur = 0;
  for (int s = 0; s < 16; ++s) {
    float4 a0, a1;
    const bool pf = (s < 15);
    if (pf) {
#pragma unroll
      for (int q = 0; q < 3; ++q) {
        int lin = q * 512 + t;
        gload16(Wt + (s + 1) * 24576 + ny * 12288 + lin * 8, &Bs[cur ^ 1][lin * 8]);
      }
      a0 = *reinterpret_cast<const float4*>(asrc + (s + 1) * 64);
      a1 = *reinterpret_cast<const float4*>(asrc + (s + 1) * 64 + 4);
    }
#pragma unroll
    for (int kk = 0; kk < 2; ++kk) {
      f16x8 af0 = frag_ld<128>(As[cur], rh + (lane & 15), kk * 32 + (lane >> 4) * 8);
      f16x8 af1 = frag_ld<128>(As[cur], rh + 16 + (lane & 15), kk * 32 + (lane >> 4) * 8);
#pragma unroll
      for (int fc = 0; fc < 3; ++fc) {
        f16x8 bw = frag_ld<128>(Bs[cur], cq + fc * 16 + (lane & 15), kk * 32 + (lane >> 4) * 8);
        acc[0][fc] = mfma16(af0, bw, acc[0][fc]);
        acc[1][fc] = mfma16(af1, bw, acc[1][fc]);
      }
    }
    if (pf) {
      uint4 o = {pack2(a0.x, a0.y), pack2(a0.z, a0.w), pack2(a1.x, a1.y), pack2(a1.z, a1.w)};
      *reinterpret_cast<uint4*>(&As[cur ^ 1][adst]) = o;
    }
    __syncthreads();
    cur ^= 1;
  }
  // outputs
#pragma unroll
  for (int fi = 0; fi < 2; ++fi)
#pragma unroll
    for (int fc = 0; fc < 3; ++fc) {
      int gcol = ny * 192 + cq + fc * 16 + (lane & 15);
      int w = gcol >> 7, h = gcol & 127;
      int i0 = mt * 64 + rh + fi * 16 + (lane >> 4) * 4;
      if (w < 2) {
        u16* P = w ? Kb : Qb;
#pragma unroll
        for (int r = 0; r < 4; ++r) {
          int i = i0 + r;
          P[(size_t)i * 128 + (h ^ ((i & 7) << 3))] = f2h(acc[fi][fc][r]);
        }
      } else {
        int bb = i0 >> 11, jt = (i0 >> 6) & 31, tl = i0 & 63;
        ushort4 o = {f2h(acc[fi][fc][0]), f2h(acc[fi][fc][1]),
                     f2h(acc[fi][fc][2]), f2h(acc[fi][fc][3])};
        size_t el = ((size_t)(bb * 32 + jt) * 128 + h) * 64 + (tl ^ ((h & 7) << 3));
        *reinterpret_cast<ushort4*>(Vtb + el) = o;
      }
    }
}

__device__ inline void merge_ml(float& m, float& l, float m2, float l2) {
  float mn = fmaxf(m, m2);
  float a = (m > -1e37f) ? l * __expf(m - mn) : 0.f;
  float b = (m2 > -1e37f) ? l2 * __expf(m2 - mn) : 0.f;
  m = mn;
  l = a + b;
}

// --------- stats pass: K-frags in regs, Q tiles dbuf via gload_lds -----------
__global__ __launch_bounds__(256, 2) void k_statsA(const u16* __restrict__ Qb,
                                                   const u16* __restrict__ Kb,
                                                   float* __restrict__ mpart,
                                                   float* __restrict__ lpart) {
  __shared__ __align__(16) u16 Qs[2][128 * 128];  // 2x32KB
  const int id = blockIdx.y * 64 + blockIdx.x;
  const int bb = id & 7, z = (id >> 3) & 7, sl = id >> 6;
  const int t = threadIdx.x, lane = t & 63, wj = (t >> 6) * 32;
  f32x4 zero = {0.f, 0.f, 0.f, 0.f};

  for (int ph = 0; ph < 2; ++ph) {
    const int jt = ph ? 15 - z : z;
    __syncthreads();  // prev-phase readers done before restaging Qs[0]
#pragma unroll
    for (int q = 0; q < 8; ++q) {
      int lin = q * 256 + t;
      gload16(Kb + ((size_t)bb * SEQ + jt * 128) * 128 + lin * 8, &Qs[0][lin * 8]);
    }
    __syncthreads();
    f16x8 af[2][4];
#pragma unroll
    for (int fj = 0; fj < 2; ++fj)
#pragma unroll
      for (int kk = 0; kk < 4; ++kk)
        af[fj][kk] = frag_ld<256>(Qs[0], wj + fj * 16 + (lane & 15), kk * 32 + (lane >> 4) * 8);
    float m[2][4], l[2][4];
#pragma unroll
    for (int a = 0; a < 2; ++a)
#pragma unroll
      for (int r = 0; r < 4; ++r) {
        m[a][r] = -INFINITY;
        l[a][r] = 0.f;
      }
    const int it0 = jt + ((sl - jt) & 7);
    int cur = 1;
    if (it0 < 16) {
#pragma unroll
      for (int q = 0; q < 8; ++q) {
        int lin = q * 256 + t;
        gload16(Qb + ((size_t)bb * SEQ + it0 * 128) * 128 + lin * 8, &Qs[1][lin * 8]);
      }
      for (int it = it0; it < 16; it += 8) {
        __syncthreads();  // stage(cur) landed; af reads + prev reads drained
        if (it + 8 < 16) {
#pragma unroll
          for (int q = 0; q < 8; ++q) {
            int lin = q * 256 + t;
            gload16(Qb + ((size_t)bb * SEQ + (it + 8) * 128) * 128 + lin * 8,
                    &Qs[cur ^ 1][lin * 8]);
          }
        }
        f32x4 acc[2][8];
#pragma unroll
        for (int a = 0; a < 2; ++a)
#pragma unroll
          for (int b = 0; b < 8; ++b) acc[a][b] = zero;
#pragma unroll
        for (int kk = 0; kk < 4; ++kk)
#pragma unroll
          for (int fi = 0; fi < 8; ++fi) {
            f16x8 bq = frag_ld<256>(Qs[cur], fi * 16 + (lane & 15), kk * 32 + (lane >> 4) * 8);
            acc[0][fi] = mfma16(af[0][kk], bq, acc[0][fi]);
            acc[1][fi] = mfma16(af[1][kk], bq, acc[1][fi]);
          }
#pragma unroll
        for (int fj = 0; fj < 2; ++fj)
#pragma unroll
          for (int r = 0; r < 4; ++r) {
            int jg = jt * 128 + wj + fj * 16 + (lane >> 4) * 4 + r;
            float v[8];
            float vmax = -INFINITY;
#pragma unroll
            for (int fi = 0; fi < 8; ++fi) {
              int ig = it * 128 + fi * 16 + (lane & 15);
              v[fi] = (ig >= jg) ? acc[fj][fi][r] : -INFINITY;
              vmax = fmaxf(vmax, v[fi]);
            }
            if (vmax > -1e37f) {
              float mn = fmaxf(m[fj][r], vmax);
              float sc = (m[fj][r] > -1e37f) ? __expf(m[fj][r] - mn) : 0.f;
              float ss = 0.f;
#pragma unroll
              for (int fi = 0; fi < 8; ++fi)
                ss += (v[fi] > -1e37f) ? __expf(v[fi] - mn) : 0.f;
              l[fj][r] = l[fj][r] * sc + ss;
              m[fj][r] = mn;
            }
          }
        cur ^= 1;
      }
    }
#pragma unroll
    for (int fj = 0; fj < 2; ++fj)
#pragma unroll
      for (int r = 0; r < 4; ++r)
        for (int msk = 1; msk <= 8; msk <<= 1) {
          float m2 = __shfl_xor(m[fj][r], msk);
          float l2 = __shfl_xor(l[fj][r], msk);
          merge_ml(m[fj][r], l[fj][r], m2, l2);
        }
    if ((lane & 15) == 0) {
#pragma unroll
      for (int fj = 0; fj < 2; ++fj)
#pragma unroll
        for (int r = 0; r < 4; ++r) {
          int j = jt * 128 + wj + fj * 16 + (lane >> 4) * 4 + r;
          size_t idx = (size_t)sl * (NB * SEQ) + (size_t)bb * SEQ + j;
          mpart[idx] = m[fj][r];
          lpart[idx] = l[fj][r];
        }
    }
  }
}

__global__ __launch_bounds__(256) void k_stats_reduce(const float* __restrict__ mpart,
                                                      const float* __restrict__ lpart,
                                                      float* __restrict__ Mg,
                                                      float* __restrict__ RLg) {
  int idx = blockIdx.x * 256 + threadIdx.x;
  float m = -INFINITY;
#pragma unroll
  for (int sl = 0; sl < NSL; sl++) m = fmaxf(m, mpart[sl * (NB * SEQ) + idx]);
  float l = 0.f;
#pragma unroll
  for (int sl = 0; sl < NSL; sl++) {
    float ms = mpart[sl * (NB * SEQ) + idx];
    if (ms > -1e37f) l += lpart[sl * (NB * SEQ) + idx] * __expf(ms - m);
  }
  Mg[idx] = m;
  RLg[idx] = 1.0f / l;
}

// --------- PV pass: K/V dbuf gload_lds; P overlays dead K buffer -------------
__global__ __launch_bounds__(256, 2) void k_passB(const u16* __restrict__ Qb,
                                                  const u16* __restrict__ Kb,
                                                  const u16* __restrict__ Vtb,
                                                  const float* __restrict__ Mg,
                                                  const float* __restrict__ RLg,
                                                  u16* __restrict__ opart) {
  __shared__ __align__(16) u16 Ks2[2][64 * 128];  // 2x16KB
  __shared__ __align__(16) u16 Vs2[2][128 * 64];  // 2x16KB
  const int id = blockIdx.y * 64 + blockIdx.x;
  const int bb = id & 7, z = (id >> 3) & 7, sl = id >> 6;
  const int t = threadIdx.x, lane = t & 63, wi = (t >> 6) * 32;
  f32x4 zero = {0.f, 0.f, 0.f, 0.f};

  auto stageKV = [&](int jt, int b) {
#pragma unroll
    for (int q = 0; q < 4; ++q) {
      int lin = q * 256 + t;
      gload16(Kb + ((size_t)bb * SEQ + jt * 64) * 128 + lin * 8, &Ks2[b][lin * 8]);
    }
#pragma unroll
    for (int q = 0; q < 4; ++q) {
      int lin = q * 256 + t;
      gload16(Vtb + ((size_t)bb * 32 + jt) * 8192 + lin * 8, &Vs2[b][lin * 8]);
    }
  };

  for (int ph = 0; ph < 2; ++ph) {
    const int it = ph ? 15 - z : z;
    f16x8 qf[2][4];
#pragma unroll
    for (int fi = 0; fi < 2; ++fi)
#pragma unroll
      for (int kk = 0; kk < 4; ++kk) {
        size_t gi = (size_t)bb * SEQ + it * 128 + wi + fi * 16 + (lane & 15);
        int e0 = kk * 32 + (lane >> 4) * 8;
        qf[fi][kk] = *reinterpret_cast<const f16x8*>(Qb + gi * 128 + (e0 ^ (((int)gi & 7) << 3)));
      }
    f32x4 accO[2][8];
#pragma unroll
    for (int a = 0; a < 2; ++a)
#pragma unroll
      for (int b = 0; b < 8; ++b) accO[a][b] = zero;
    const int jtmax = 2 * it + 1;
    int cur = 0;
    __syncthreads();  // prev-phase readers done
    if (sl <= jtmax) stageKV(sl, 0);
    for (int jt = sl; jt <= jtmax; jt += 8) {
      __syncthreads();  // stage(cur) landed everywhere
      float mjv[4], rlv[4];
#pragma unroll
      for (int fj = 0; fj < 4; ++fj) {
        int jg = jt * 64 + fj * 16 + (lane & 15);
        mjv[fj] = Mg[bb * SEQ + jg];
        rlv[fj] = RLg[bb * SEQ + jg];
      }
      f32x4 accS[2][4];
#pragma unroll
      for (int a = 0; a < 2; ++a)
#pragma unroll
        for (int b = 0; b < 4; ++b) accS[a][b] = zero;
#pragma unroll
      for (int kk = 0; kk < 4; ++kk)
#pragma unroll
        for (int fj = 0; fj < 4; ++fj) {
          f16x8 bk = frag_ld<256>(Ks2[cur], fj * 16 + (lane & 15), kk * 32 + (lane >> 4) * 8);
          accS[0][fj] = mfma16(qf[0][kk], bk, accS[0][fj]);
          accS[1][fj] = mfma16(qf[1][kk], bk, accS[1][fj]);
        }
      __syncthreads();  // all waves done reading Ks2[cur]
      if (jt + 8 <= jtmax) stageKV(jt + 8, cur ^ 1);  // overlaps P+PV, drains at next top
      u16* Ps = Ks2[cur];
#pragma unroll
      for (int fj = 0; fj < 4; ++fj) {
        int jloc = fj * 16 + (lane & 15);
        int jg = jt * 64 + jloc;
        float mj = mjv[fj], rlj = rlv[fj];
#pragma unroll
        for (int fi = 0; fi < 2; ++fi)
#pragma unroll
          for (int r = 0; r < 4; ++r) {
            int iloc = wi + fi * 16 + (lane >> 4) * 4 + r;
            int ig = it * 128 + iloc;
            float p = __expf(accS[fi][fj][r] - mj) * rlj;
            if (ig < jg) p = 0.f;
            Ps[iloc * 64 + (jloc ^ ((iloc & 7) << 3))] = f2h(p);
          }
      }
      // PV: wave-private P rows -> no barrier needed (lgkm ordering only)
#pragma unroll
      for (int ks = 0; ks < 2; ++ks) {
        f16x8 pa0 = frag_ld<128>(Ps, wi + (lane & 15), ks * 32 + (lane >> 4) * 8);
        f16x8 pa1 = frag_ld<128>(Ps, wi + 16 + (lane & 15), ks * 32 + (lane >> 4) * 8);
#pragma unroll
        for (int fh = 0; fh < 8; ++fh) {
          f16x8 bv = frag_ld<128>(Vs2[cur], fh * 16 + (lane & 15), ks * 32 + (lane >> 4) * 8);
          accO[0][fh] = mfma16(pa0, bv, accO[0][fh]);
          accO[1][fh] = mfma16(pa1, bv, accO[1][fh]);
        }
      }
      cur ^= 1;
    }
#pragma unroll
    for (int fi = 0; fi < 2; ++fi)
#pragma unroll
      for (int fh = 0; fh < 8; ++fh)
#pragma unroll
        for (int r = 0; r < 4; ++r) {
          int ig = it * 128 + wi + fi * 16 + (lane >> 4) * 4 + r;
          int h = fh * 16 + (lane & 15);
          opart[(((size_t)sl * NB + bb) * SEQ + ig) * HD + h] = f2h(accO[fi][fh][r]);
        }
  }
}

__global__ __launch_bounds__(256) void k_reduceB(const u16* __restrict__ opart,
                                                 float* __restrict__ out) {
  size_t base = ((size_t)blockIdx.x * 256 + threadIdx.x) * 8;
  const size_t S = (size_t)NB * SEQ * HD;
  float s[8];
#pragma unroll
  for (int j = 0; j < 8; j++) s[j] = 0.f;
#pragma unroll
  for (int sl = 0; sl < NSL; sl++) {
    f16x8 v = *reinterpret_cast<const f16x8*>(opart + sl * S + base);
#pragma unroll
    for (int j = 0; j < 8; j++) s[j] += (float)v[j];
  }
  float4 o0 = {s[0], s[1], s[2], s[3]};
  float4 o1 = {s[4], s[5], s[6], s[7]};
  *reinterpret_cast<float4*>(out + base) = o0;
  *reinterpret_cast<float4*>(out + base + 4) = o1;
}

extern "C" void kernel_launch(void* const* d_in, const int* in_sizes, int n_in,
                              void* d_out, int out_size, void* d_ws, size_t ws_size,
                              hipStream_t stream) {
  (void)in_sizes; (void)n_in; (void)out_size; (void)ws_size;
  const float* x = (const float*)d_in[0];
  const float* Wk = (const float*)d_in[1];
  const float* Wq = (const float*)d_in[2];
  const float* Wv = (const float*)d_in[3];
  float* out = (float*)d_out;
  char* ws = (char*)d_ws;

  u16* Wt = (u16*)(ws + 0);                //   786,432 B  (pre-swizzled tiles)
  u16* Qb = (u16*)(ws + 786432);           // 4,194,304 B  (pre-swizzled)
  u16* Kb = (u16*)(ws + 4980736);          // 4,194,304 B  (pre-swizzled)
  u16* Vtb = (u16*)(ws + 9175040);         // 4,194,304 B  (pre-swizzled tiles)
  float* mpart = (float*)(ws + 13369344);  //   524,288 B
  float* lpart = (float*)(ws + 13893632);  //   524,288 B
  float* Mg = (float*)(ws + 14417920);     //    65,536 B
  float* RLg = (float*)(ws + 14483456);    //    65,536 B
  u16* opart = (u16*)(ws + 14548992);      // 33,554,432 B (total ~45.9 MB)

  k_cvt_w<<<384, 256, 0, stream>>>(Wq, Wk, Wv, Wt);
  k_proj<<<dim3(256, 2), 512, 0, stream>>>(x, Wt, Qb, Kb, Vtb);
  k_statsA<<<dim3(64, 8), 256, 0, stream>>>(Qb, Kb, mpart, lpart);
  k_stats_reduce<<<64, 256, 0, stream>>>(mpart, lpart, Mg, RLg);
  k_passB<<<dim3(64, 8), 256, 0, stream>>>(Qb, Kb, Vtb, Mg, RLg, opart);
  k_reduceB<<<1024, 256, 0, stream>>>(opart, out);
}

// Round 4
// 83.819 us; speedup vs baseline: 1.5453x; 1.0101x over previous
//
#include <hip/hip_runtime.h>

typedef unsigned short u16;
typedef unsigned int u32;
typedef _Float16 f16;
typedef __attribute__((ext_vector_type(8))) _Float16 f16x8;
typedef __attribute__((ext_vector_type(4))) float f32x4;

constexpr int SEQ = 2048;
constexpr int EMBD = 1024;
constexpr int HD = 128;
constexpr int NB = 8;
constexpr int NSL = 8;

__device__ inline u16 f2h(float f) { return __builtin_bit_cast(u16, (f16)f); }
__device__ inline u32 pack2(float a, float b) { return (u32)f2h(a) | ((u32)f2h(b) << 16); }

__device__ inline f32x4 mfma16(f16x8 a, f16x8 b, f32x4 c) {
  return __builtin_amdgcn_mfma_f32_16x16x32_f16(a, b, c, 0, 0, 0);
}

// 16B global -> LDS direct (no VGPR round trip)
__device__ __forceinline__ void gload16(const u16* g, u16* l) {
  __builtin_amdgcn_global_load_lds(
      (const __attribute__((address_space(1))) u32*)g,
      (__attribute__((address_space(3))) u32*)l, 16, 0, 0);
}

// Swizzled fragment read: tiles are stored (in LDS *and* in global scratch)
// row-major with within-row chunk XOR: byte ^= (row&7)<<4  (element ^= (row&7)<<3).
template<int RB>
__device__ inline f16x8 frag_ld(const u16* lds, int row, int e) {
  int byte = row * RB + ((e * 2) ^ ((row & 7) << 4));
  return *reinterpret_cast<const f16x8*>(reinterpret_cast<const char*>(lds) + byte);
}

// --------- weights: Wt[k0t][H][e] pre-swizzled tiles, H = w*128+h, 48KB/tile --
__global__ __launch_bounds__(256) void k_cvt_w(const float* __restrict__ Wq,
                                               const float* __restrict__ Wk,
                                               const float* __restrict__ Wv,
                                               u16* __restrict__ Wt) {
  int t = blockIdx.x * 256 + threadIdx.x;  // 98304
  int e0 = (t & 255) * 4;
  int H = t >> 8;  // 0..383
  int w = H >> 7, h = H & 127;
  const float* W = (w == 0) ? Wq : (w == 1) ? Wk : Wv;
  ushort4 o;
  o.x = f2h(W[(size_t)(e0 + 0) * HD + h]);
  o.y = f2h(W[(size_t)(e0 + 1) * HD + h]);
  o.z = f2h(W[(size_t)(e0 + 2) * HD + h]);
  o.w = f2h(W[(size_t)(e0 + 3) * HD + h]);
  int k0t = e0 >> 6, ec = e0 & 63;
  size_t el = (size_t)(k0t * 384 + H) * 64 + (ec ^ ((H & 7) << 3));
  *reinterpret_cast<ushort4*>(Wt + el) = o;
}

// --------- fused projections: 64 rows x 192 cols per block, 2-phase dbuf -----
// Q,K written pre-swizzled row-major; V written pre-swizzled transposed tiles.
__global__ __launch_bounds__(512, 4) void k_proj(const float* __restrict__ x,
                                                 const u16* __restrict__ Wt,
                                                 u16* __restrict__ Qb,
                                                 u16* __restrict__ Kb,
                                                 u16* __restrict__ Vtb) {
  __shared__ __align__(16) u16 As[2][64 * 64];    // 16KB
  __shared__ __align__(16) u16 Bs[2][192 * 64];   // 48KB
  const int mt = blockIdx.x, ny = blockIdx.y;
  const int t = threadIdx.x, lane = t & 63, wave = t >> 6;
  const int rh = (wave & 1) * 32, cq = (wave >> 1) * 48;
  const int ar = t >> 3, ac = t & 7;
  const float* asrc = x + (size_t)(mt * 64 + ar) * EMBD + ac * 8;
  const int adst = ar * 64 + ((ac * 8) ^ ((ar & 7) << 3));
  f32x4 zero = {0.f, 0.f, 0.f, 0.f};
  f32x4 acc[2][3];
#pragma unroll
  for (int a = 0; a < 2; ++a)
#pragma unroll
    for (int b = 0; b < 3; ++b) acc[a][b] = zero;

  // prologue: stage k-step 0
  {
#pragma unroll
    for (int q = 0; q < 3; ++q) {
      int lin = q * 512 + t;
      gload16(Wt + ny * 12288 + lin * 8, &Bs[0][lin * 8]);
    }
    float4 a0 = *reinterpret_cast<const float4*>(asrc);
    float4 a1 = *reinterpret_cast<const float4*>(asrc + 4);
    uint4 o = {pack2(a0.x, a0.y), pack2(a0.z, a0.w), pack2(a1.x, a1.y), pack2(a1.z, a1.w)};
    *reinterpret_cast<uint4*>(&As[0][adst]) = o;
  }
  __syncthreads();
  int cur = 0;
  for (int s = 0; s < 16; ++s) {
    float4 a0, a1;
    const bool pf = (s < 15);
    if (pf) {
#pragma unroll
      for (int q = 0; q < 3; ++q) {
        int lin = q * 512 + t;
        gload16(Wt + (s + 1) * 24576 + ny * 12288 + lin * 8, &Bs[cur ^ 1][lin * 8]);
      }
      a0 = *reinterpret_cast<const float4*>(asrc + (s + 1) * 64);
      a1 = *reinterpret_cast<const float4*>(asrc + (s + 1) * 64 + 4);
    }
#pragma unroll
    for (int kk = 0; kk < 2; ++kk) {
      f16x8 af0 = frag_ld<128>(As[cur], rh + (lane & 15), kk * 32 + (lane >> 4) * 8);
      f16x8 af1 = frag_ld<128>(As[cur], rh + 16 + (lane & 15), kk * 32 + (lane >> 4) * 8);
#pragma unroll
      for (int fc = 0; fc < 3; ++fc) {
        f16x8 bw = frag_ld<128>(Bs[cur], cq + fc * 16 + (lane & 15), kk * 32 + (lane >> 4) * 8);
        acc[0][fc] = mfma16(af0, bw, acc[0][fc]);
        acc[1][fc] = mfma16(af1, bw, acc[1][fc]);
      }
    }
    if (pf) {
      uint4 o = {pack2(a0.x, a0.y), pack2(a0.z, a0.w), pack2(a1.x, a1.y), pack2(a1.z, a1.w)};
      *reinterpret_cast<uint4*>(&As[cur ^ 1][adst]) = o;
    }
    __syncthreads();
    cur ^= 1;
  }
  // outputs
#pragma unroll
  for (int fi = 0; fi < 2; ++fi)
#pragma unroll
    for (int fc = 0; fc < 3; ++fc) {
      int gcol = ny * 192 + cq + fc * 16 + (lane & 15);
      int w = gcol >> 7, h = gcol & 127;
      int i0 = mt * 64 + rh + fi * 16 + (lane >> 4) * 4;
      if (w < 2) {
        u16* P = w ? Kb : Qb;
#pragma unroll
        for (int r = 0; r < 4; ++r) {
          int i = i0 + r;
          P[(size_t)i * 128 + (h ^ ((i & 7) << 3))] = f2h(acc[fi][fc][r]);
        }
      } else {
        int bb = i0 >> 11, jt = (i0 >> 6) & 31, tl = i0 & 63;
        ushort4 o = {f2h(acc[fi][fc][0]), f2h(acc[fi][fc][1]),
                     f2h(acc[fi][fc][2]), f2h(acc[fi][fc][3])};
        size_t el = ((size_t)(bb * 32 + jt) * 128 + h) * 64 + (tl ^ ((h & 7) << 3));
        *reinterpret_cast<ushort4*>(Vtb + el) = o;
      }
    }
}

__device__ inline void merge_ml(float& m, float& l, float m2, float l2) {
  float mn = fmaxf(m, m2);
  float a = (m > -1e37f) ? l * __expf(m - mn) : 0.f;
  float b = (m2 > -1e37f) ? l2 * __expf(m2 - mn) : 0.f;
  m = mn;
  l = a + b;
}

// --------- stats pass: K-frags in regs, Q tiles dbuf via gload_lds -----------
__global__ __launch_bounds__(256, 2) void k_statsA(const u16* __restrict__ Qb,
                                                   const u16* __restrict__ Kb,
                                                   float* __restrict__ mpart,
                                                   float* __restrict__ lpart) {
  __shared__ __align__(16) u16 Qs[2][128 * 128];  // 2x32KB
  const int id = blockIdx.y * 64 + blockIdx.x;
  const int bb = id & 7, z = (id >> 3) & 7, sl = id >> 6;
  const int t = threadIdx.x, lane = t & 63, wj = (t >> 6) * 32;
  f32x4 zero = {0.f, 0.f, 0.f, 0.f};

  for (int ph = 0; ph < 2; ++ph) {
    const int jt = ph ? 15 - z : z;
    __syncthreads();  // prev-phase readers done before restaging Qs[0]
#pragma unroll
    for (int q = 0; q < 8; ++q) {
      int lin = q * 256 + t;
      gload16(Kb + ((size_t)bb * SEQ + jt * 128) * 128 + lin * 8, &Qs[0][lin * 8]);
    }
    __syncthreads();
    f16x8 af[2][4];
#pragma unroll
    for (int fj = 0; fj < 2; ++fj)
#pragma unroll
      for (int kk = 0; kk < 4; ++kk)
        af[fj][kk] = frag_ld<256>(Qs[0], wj + fj * 16 + (lane & 15), kk * 32 + (lane >> 4) * 8);
    float m[2][4], l[2][4];
#pragma unroll
    for (int a = 0; a < 2; ++a)
#pragma unroll
      for (int r = 0; r < 4; ++r) {
        m[a][r] = -INFINITY;
        l[a][r] = 0.f;
      }
    const int it0 = jt + ((sl - jt) & 7);
    int cur = 1;
    if (it0 < 16) {
#pragma unroll
      for (int q = 0; q < 8; ++q) {
        int lin = q * 256 + t;
        gload16(Qb + ((size_t)bb * SEQ + it0 * 128) * 128 + lin * 8, &Qs[1][lin * 8]);
      }
      for (int it = it0; it < 16; it += 8) {
        __syncthreads();  // stage(cur) landed; af reads + prev reads drained
        if (it + 8 < 16) {
#pragma unroll
          for (int q = 0; q < 8; ++q) {
            int lin = q * 256 + t;
            gload16(Qb + ((size_t)bb * SEQ + (it + 8) * 128) * 128 + lin * 8,
                    &Qs[cur ^ 1][lin * 8]);
          }
        }
        f32x4 acc[2][8];
#pragma unroll
        for (int a = 0; a < 2; ++a)
#pragma unroll
          for (int b = 0; b < 8; ++b) acc[a][b] = zero;
        __builtin_amdgcn_s_setprio(1);
#pragma unroll
        for (int kk = 0; kk < 4; ++kk)
#pragma unroll
          for (int fi = 0; fi < 8; ++fi) {
            f16x8 bq = frag_ld<256>(Qs[cur], fi * 16 + (lane & 15), kk * 32 + (lane >> 4) * 8);
            acc[0][fi] = mfma16(af[0][kk], bq, acc[0][fi]);
            acc[1][fi] = mfma16(af[1][kk], bq, acc[1][fi]);
          }
        __builtin_amdgcn_s_setprio(0);
#pragma unroll
        for (int fj = 0; fj < 2; ++fj)
#pragma unroll
          for (int r = 0; r < 4; ++r) {
            int jg = jt * 128 + wj + fj * 16 + (lane >> 4) * 4 + r;
            float v[8];
            float vmax = -INFINITY;
#pragma unroll
            for (int fi = 0; fi < 8; ++fi) {
              int ig = it * 128 + fi * 16 + (lane & 15);
              v[fi] = (ig >= jg) ? acc[fj][fi][r] : -INFINITY;
              vmax = fmaxf(vmax, v[fi]);
            }
            if (vmax > -1e37f) {
              float mn = fmaxf(m[fj][r], vmax);
              float sc = (m[fj][r] > -1e37f) ? __expf(m[fj][r] - mn) : 0.f;
              float ss = 0.f;
#pragma unroll
              for (int fi = 0; fi < 8; ++fi)
                ss += (v[fi] > -1e37f) ? __expf(v[fi] - mn) : 0.f;
              l[fj][r] = l[fj][r] * sc + ss;
              m[fj][r] = mn;
            }
          }
        cur ^= 1;
      }
    }
#pragma unroll
    for (int fj = 0; fj < 2; ++fj)
#pragma unroll
      for (int r = 0; r < 4; ++r)
        for (int msk = 1; msk <= 8; msk <<= 1) {
          float m2 = __shfl_xor(m[fj][r], msk);
          float l2 = __shfl_xor(l[fj][r], msk);
          merge_ml(m[fj][r], l[fj][r], m2, l2);
        }
    if ((lane & 15) == 0) {
#pragma unroll
      for (int fj = 0; fj < 2; ++fj)
#pragma unroll
        for (int r = 0; r < 4; ++r) {
          int j = jt * 128 + wj + fj * 16 + (lane >> 4) * 4 + r;
          size_t idx = (size_t)sl * (NB * SEQ) + (size_t)bb * SEQ + j;
          mpart[idx] = m[fj][r];
          lpart[idx] = l[fj][r];
        }
    }
  }
}

// C_j = m_j + ln(l_j): single stat per column for passB (p = exp(S - C_j)).
__global__ __launch_bounds__(256) void k_stats_reduce(const float* __restrict__ mpart,
                                                      const float* __restrict__ lpart,
                                                      float* __restrict__ Cg) {
  int idx = blockIdx.x * 256 + threadIdx.x;
  float m = -INFINITY;
#pragma unroll
  for (int sl = 0; sl < NSL; sl++) m = fmaxf(m, mpart[sl * (NB * SEQ) + idx]);
  float l = 0.f;
#pragma unroll
  for (int sl = 0; sl < NSL; sl++) {
    float ms = mpart[sl * (NB * SEQ) + idx];
    if (ms > -1e37f) l += lpart[sl * (NB * SEQ) + idx] * __expf(ms - m);
  }
  Cg[idx] = m + __logf(l);
}

// --------- PV pass: dedicated Ps buffer, ONE barrier per jt, early stage -----
__global__ __launch_bounds__(256, 2) void k_passB(const u16* __restrict__ Qb,
                                                  const u16* __restrict__ Kb,
                                                  const u16* __restrict__ Vtb,
                                                  const float* __restrict__ Cg,
                                                  u16* __restrict__ opart) {
  __shared__ __align__(16) u16 Ks2[2][64 * 128];  // 2x16KB
  __shared__ __align__(16) u16 Vs2[2][128 * 64];  // 2x16KB
  __shared__ __align__(16) u16 Ps[128 * 64];      // 16KB (80KB total, 2 blk/CU)
  const int id = blockIdx.y * 64 + blockIdx.x;
  const int bb = id & 7, z = (id >> 3) & 7, sl = id >> 6;
  const int t = threadIdx.x, lane = t & 63, wi = (t >> 6) * 32;
  f32x4 zero = {0.f, 0.f, 0.f, 0.f};

  auto stageKV = [&](int jt, int b) {
#pragma unroll
    for (int q = 0; q < 4; ++q) {
      int lin = q * 256 + t;
      gload16(Kb + ((size_t)bb * SEQ + jt * 64) * 128 + lin * 8, &Ks2[b][lin * 8]);
    }
#pragma unroll
    for (int q = 0; q < 4; ++q) {
      int lin = q * 256 + t;
      gload16(Vtb + ((size_t)bb * 32 + jt) * 8192 + lin * 8, &Vs2[b][lin * 8]);
    }
  };

  for (int ph = 0; ph < 2; ++ph) {
    const int it = ph ? 15 - z : z;
    f16x8 qf[2][4];
#pragma unroll
    for (int fi = 0; fi < 2; ++fi)
#pragma unroll
      for (int kk = 0; kk < 4; ++kk) {
        size_t gi = (size_t)bb * SEQ + it * 128 + wi + fi * 16 + (lane & 15);
        int e0 = kk * 32 + (lane >> 4) * 8;
        qf[fi][kk] = *reinterpret_cast<const f16x8*>(Qb + gi * 128 + (e0 ^ (((int)gi & 7) << 3)));
      }
    f32x4 accO[2][8];
#pragma unroll
    for (int a = 0; a < 2; ++a)
#pragma unroll
      for (int b = 0; b < 8; ++b) accO[a][b] = zero;
    const int jtmax = 2 * it + 1;
    __syncthreads();  // prev-phase LDS readers done
    if (sl <= jtmax) stageKV(sl, 0);
    int cur = 0;
    for (int jt = sl; jt <= jtmax; jt += 8) {
      __syncthreads();  // vmcnt(0): stage(jt) landed; prev readers of cur done
      if (jt + 8 <= jtmax) stageKV(jt + 8, cur ^ 1);  // hides under QK+exp+PV
      float cj[4];
#pragma unroll
      for (int fj = 0; fj < 4; ++fj)
        cj[fj] = Cg[bb * SEQ + jt * 64 + fj * 16 + (lane & 15)];
      f32x4 accS[2][4];
#pragma unroll
      for (int a = 0; a < 2; ++a)
#pragma unroll
        for (int b = 0; b < 4; ++b) accS[a][b] = zero;
      __builtin_amdgcn_s_setprio(1);
#pragma unroll
      for (int kk = 0; kk < 4; ++kk)
#pragma unroll
        for (int fj = 0; fj < 4; ++fj) {
          f16x8 bk = frag_ld<256>(Ks2[cur], fj * 16 + (lane & 15), kk * 32 + (lane >> 4) * 8);
          accS[0][fj] = mfma16(qf[0][kk], bk, accS[0][fj]);
          accS[1][fj] = mfma16(qf[1][kk], bk, accS[1][fj]);
        }
      __builtin_amdgcn_s_setprio(0);
      // P = exp(S - C_j), causal-masked; wave-private rows of Ps
#pragma unroll
      for (int fj = 0; fj < 4; ++fj) {
        int jloc = fj * 16 + (lane & 15);
        int jg = jt * 64 + jloc;
        float c = cj[fj];
#pragma unroll
        for (int fi = 0; fi < 2; ++fi)
#pragma unroll
          for (int r = 0; r < 4; ++r) {
            int iloc = wi + fi * 16 + (lane >> 4) * 4 + r;
            int ig = it * 128 + iloc;
            float p = __expf(accS[fi][fj][r] - c);
            if (ig < jg) p = 0.f;
            Ps[iloc * 64 + (jloc ^ ((iloc & 7) << 3))] = f2h(p);
          }
      }
      // PV: wave-private P rows -> lgkm ordering only, no barrier
      __builtin_amdgcn_s_setprio(1);
#pragma unroll
      for (int ks = 0; ks < 2; ++ks) {
        f16x8 pa0 = frag_ld<128>(Ps, wi + (lane & 15), ks * 32 + (lane >> 4) * 8);
        f16x8 pa1 = frag_ld<128>(Ps, wi + 16 + (lane & 15), ks * 32 + (lane >> 4) * 8);
#pragma unroll
        for (int fh = 0; fh < 8; ++fh) {
          f16x8 bv = frag_ld<128>(Vs2[cur], fh * 16 + (lane & 15), ks * 32 + (lane >> 4) * 8);
          accO[0][fh] = mfma16(pa0, bv, accO[0][fh]);
          accO[1][fh] = mfma16(pa1, bv, accO[1][fh]);
        }
      }
      __builtin_amdgcn_s_setprio(0);
      cur ^= 1;
    }
#pragma unroll
    for (int fi = 0; fi < 2; ++fi)
#pragma unroll
      for (int fh = 0; fh < 8; ++fh)
#pragma unroll
        for (int r = 0; r < 4; ++r) {
          int ig = it * 128 + wi + fi * 16 + (lane >> 4) * 4 + r;
          int h = fh * 16 + (lane & 15);
          opart[(((size_t)sl * NB + bb) * SEQ + ig) * HD + h] = f2h(accO[fi][fh][r]);
        }
  }
}

__global__ __launch_bounds__(256) void k_reduceB(const u16* __restrict__ opart,
                                                 float* __restrict__ out) {
  size_t base = ((size_t)blockIdx.x * 256 + threadIdx.x) * 8;
  const size_t S = (size_t)NB * SEQ * HD;
  float s[8];
#pragma unroll
  for (int j = 0; j < 8; j++) s[j] = 0.f;
#pragma unroll
  for (int sl = 0; sl < NSL; sl++) {
    f16x8 v = *reinterpret_cast<const f16x8*>(opart + sl * S + base);
#pragma unroll
    for (int j = 0; j < 8; j++) s[j] += (float)v[j];
  }
  float4 o0 = {s[0], s[1], s[2], s[3]};
  float4 o1 = {s[4], s[5], s[6], s[7]};
  *reinterpret_cast<float4*>(out + base) = o0;
  *reinterpret_cast<float4*>(out + base + 4) = o1;
}

extern "C" void kernel_launch(void* const* d_in, const int* in_sizes, int n_in,
                              void* d_out, int out_size, void* d_ws, size_t ws_size,
                              hipStream_t stream) {
  (void)in_sizes; (void)n_in; (void)out_size; (void)ws_size;
  const float* x = (const float*)d_in[0];
  const float* Wk = (const float*)d_in[1];
  const float* Wq = (const float*)d_in[2];
  const float* Wv = (const float*)d_in[3];
  float* out = (float*)d_out;
  char* ws = (char*)d_ws;

  u16* Wt = (u16*)(ws + 0);                //   786,432 B  (pre-swizzled tiles)
  u16* Qb = (u16*)(ws + 786432);           // 4,194,304 B  (pre-swizzled)
  u16* Kb = (u16*)(ws + 4980736);          // 4,194,304 B  (pre-swizzled)
  u16* Vtb = (u16*)(ws + 9175040);         // 4,194,304 B  (pre-swizzled tiles)
  float* mpart = (float*)(ws + 13369344);  //   524,288 B
  float* lpart = (float*)(ws + 13893632);  //   524,288 B
  float* Cg = (float*)(ws + 14417920);     //    65,536 B
  u16* opart = (u16*)(ws + 14548992);      // 33,554,432 B (total ~45.9 MB)

  k_cvt_w<<<384, 256, 0, stream>>>(Wq, Wk, Wv, Wt);
  k_proj<<<dim3(256, 2), 512, 0, stream>>>(x, Wt, Qb, Kb, Vtb);
  k_statsA<<<dim3(64, 8), 256, 0, stream>>>(Qb, Kb, mpart, lpart);
  k_stats_reduce<<<64, 256, 0, stream>>>(mpart, lpart, Cg);
  k_passB<<<dim3(64, 8), 256, 0, stream>>>(Qb, Kb, Vtb, Cg, opart);
  k_reduceB<<<1024, 256, 0, stream>>>(opart, out);
}

// Round 5
// 79.146 us; speedup vs baseline: 1.6365x; 1.0590x over previous
//
#include <hip/hip_runtime.h>

typedef unsigned short u16;
typedef unsigned int u32;
typedef _Float16 f16;
typedef __attribute__((ext_vector_type(8))) _Float16 f16x8;
typedef __attribute__((ext_vector_type(4))) float f32x4;

constexpr int SEQ = 2048;
constexpr int EMBD = 1024;
constexpr int HD = 128;
constexpr int NB = 8;
constexpr int NSLS = 8;  // slices in stats pass
constexpr int NSLP = 4;  // slices in PV pass

__device__ inline u16 f2h(float f) { return __builtin_bit_cast(u16, (f16)f); }
__device__ inline u32 pack2(float a, float b) { return (u32)f2h(a) | ((u32)f2h(b) << 16); }

__device__ inline f32x4 mfma16(f16x8 a, f16x8 b, f32x4 c) {
  return __builtin_amdgcn_mfma_f32_16x16x32_f16(a, b, c, 0, 0, 0);
}

// 16B global -> LDS direct (no VGPR round trip)
__device__ __forceinline__ void gload16(const u16* g, u16* l) {
  __builtin_amdgcn_global_load_lds(
      (const __attribute__((address_space(1))) u32*)g,
      (__attribute__((address_space(3))) u32*)l, 16, 0, 0);
}

// Swizzled fragment read: tiles are stored (LDS and global scratch) row-major
// with within-row chunk XOR: byte ^= (row&7)<<4 (element ^= (row&7)<<3).
template<int RB>
__device__ inline f16x8 frag_ld(const u16* lds, int row, int e) {
  int byte = row * RB + ((e * 2) ^ ((row & 7) << 4));
  return *reinterpret_cast<const f16x8*>(reinterpret_cast<const char*>(lds) + byte);
}

// --------- weights: Wt[k0t][H][e] pre-swizzled tiles, H = w*128+h -----------
__global__ __launch_bounds__(256) void k_cvt_w(const float* __restrict__ Wq,
                                               const float* __restrict__ Wk,
                                               const float* __restrict__ Wv,
                                               u16* __restrict__ Wt) {
  int t = blockIdx.x * 256 + threadIdx.x;  // 98304
  int e0 = (t & 255) * 4;
  int H = t >> 8;  // 0..383
  int w = H >> 7, h = H & 127;
  const float* W = (w == 0) ? Wq : (w == 1) ? Wk : Wv;
  ushort4 o;
  o.x = f2h(W[(size_t)(e0 + 0) * HD + h]);
  o.y = f2h(W[(size_t)(e0 + 1) * HD + h]);
  o.z = f2h(W[(size_t)(e0 + 2) * HD + h]);
  o.w = f2h(W[(size_t)(e0 + 3) * HD + h]);
  int k0t = e0 >> 6, ec = e0 & 63;
  size_t el = (size_t)(k0t * 384 + H) * 64 + (ec ^ ((H & 7) << 3));
  *reinterpret_cast<ushort4*>(Wt + el) = o;
}

// --------- fused projections, 2-deep x register prefetch --------------------
__global__ __launch_bounds__(512, 4) void k_proj(const float* __restrict__ x,
                                                 const u16* __restrict__ Wt,
                                                 u16* __restrict__ Qb,
                                                 u16* __restrict__ Kb,
                                                 u16* __restrict__ Vtb) {
  __shared__ __align__(16) u16 As[2][64 * 64];    // 16KB
  __shared__ __align__(16) u16 Bs[2][192 * 64];   // 48KB
  const int mt = blockIdx.x, ny = blockIdx.y;
  const int t = threadIdx.x, lane = t & 63, wave = t >> 6;
  const int rh = (wave & 1) * 32, cq = (wave >> 1) * 48;
  const int ar = t >> 3, ac = t & 7;
  const float* asrc = x + (size_t)(mt * 64 + ar) * EMBD + ac * 8;
  const int adst = ar * 64 + ((ac * 8) ^ ((ar & 7) << 3));
  f32x4 zero = {0.f, 0.f, 0.f, 0.f};
  f32x4 acc[2][3];
#pragma unroll
  for (int a = 0; a < 2; ++a)
#pragma unroll
    for (int b = 0; b < 3; ++b) acc[a][b] = zero;

  float4 xe0, xe1, xo0, xo1;  // even-step / odd-step x slots
  // prologue: x(0) -> even slot -> pack; W(0) stage; issue x(1) -> odd slot
  xe0 = *reinterpret_cast<const float4*>(asrc);
  xe1 = *reinterpret_cast<const float4*>(asrc + 4);
#pragma unroll
  for (int q = 0; q < 3; ++q) {
    int lin = q * 512 + t;
    gload16(Wt + ny * 12288 + lin * 8, &Bs[0][lin * 8]);
  }
  {
    uint4 o = {pack2(xe0.x, xe0.y), pack2(xe0.z, xe0.w), pack2(xe1.x, xe1.y), pack2(xe1.z, xe1.w)};
    *reinterpret_cast<uint4*>(&As[0][adst]) = o;
  }
  xo0 = *reinterpret_cast<const float4*>(asrc + 64);
  xo1 = *reinterpret_cast<const float4*>(asrc + 68);
  __syncthreads();
#pragma unroll 2
  for (int s = 0; s < 16; ++s) {
    const int cur = s & 1;
    if (s + 1 < 16) {
#pragma unroll
      for (int q = 0; q < 3; ++q) {
        int lin = q * 512 + t;
        gload16(Wt + (s + 1) * 24576 + ny * 12288 + lin * 8, &Bs[cur ^ 1][lin * 8]);
      }
    }
    if (s + 2 < 16) {  // issue x(s+2); consumed at step s+1 -> full-step latency cover
      if (cur == 0) {
        xe0 = *reinterpret_cast<const float4*>(asrc + (s + 2) * 64);
        xe1 = *reinterpret_cast<const float4*>(asrc + (s + 2) * 64 + 4);
      } else {
        xo0 = *reinterpret_cast<const float4*>(asrc + (s + 2) * 64);
        xo1 = *reinterpret_cast<const float4*>(asrc + (s + 2) * 64 + 4);
      }
    }
    __builtin_amdgcn_s_setprio(1);
#pragma unroll
    for (int kk = 0; kk < 2; ++kk) {
      f16x8 af0 = frag_ld<128>(As[cur], rh + (lane & 15), kk * 32 + (lane >> 4) * 8);
      f16x8 af1 = frag_ld<128>(As[cur], rh + 16 + (lane & 15), kk * 32 + (lane >> 4) * 8);
#pragma unroll
      for (int fc = 0; fc < 3; ++fc) {
        f16x8 bw = frag_ld<128>(Bs[cur], cq + fc * 16 + (lane & 15), kk * 32 + (lane >> 4) * 8);
        acc[0][fc] = mfma16(af0, bw, acc[0][fc]);
        acc[1][fc] = mfma16(af1, bw, acc[1][fc]);
      }
    }
    __builtin_amdgcn_s_setprio(0);
    if (s + 1 < 16) {  // pack x(s+1) (loaded one full step ago)
      uint4 o;
      if (cur == 0)
        o = {pack2(xo0.x, xo0.y), pack2(xo0.z, xo0.w), pack2(xo1.x, xo1.y), pack2(xo1.z, xo1.w)};
      else
        o = {pack2(xe0.x, xe0.y), pack2(xe0.z, xe0.w), pack2(xe1.x, xe1.y), pack2(xe1.z, xe1.w)};
      *reinterpret_cast<uint4*>(&As[cur ^ 1][adst]) = o;
    }
    __syncthreads();
  }
  // outputs
#pragma unroll
  for (int fi = 0; fi < 2; ++fi)
#pragma unroll
    for (int fc = 0; fc < 3; ++fc) {
      int gcol = ny * 192 + cq + fc * 16 + (lane & 15);
      int w = gcol >> 7, h = gcol & 127;
      int i0 = mt * 64 + rh + fi * 16 + (lane >> 4) * 4;
      if (w < 2) {
        u16* P = w ? Kb : Qb;
#pragma unroll
        for (int r = 0; r < 4; ++r) {
          int i = i0 + r;
          P[(size_t)i * 128 + (h ^ ((i & 7) << 3))] = f2h(acc[fi][fc][r]);
        }
      } else {
        int bb = i0 >> 11, jt = (i0 >> 6) & 31, tl = i0 & 63;
        ushort4 o = {f2h(acc[fi][fc][0]), f2h(acc[fi][fc][1]),
                     f2h(acc[fi][fc][2]), f2h(acc[fi][fc][3])};
        size_t el = ((size_t)(bb * 32 + jt) * 128 + h) * 64 + (tl ^ ((h & 7) << 3));
        *reinterpret_cast<ushort4*>(Vtb + el) = o;
      }
    }
}

__device__ inline void merge_ml(float& m, float& l, float m2, float l2) {
  float mn = fmaxf(m, m2);
  float a = (m > -1e37f) ? l * __expf(m - mn) : 0.f;
  float b = (m2 > -1e37f) ? l2 * __expf(m2 - mn) : 0.f;
  m = mn;
  l = a + b;
}

// --------- stats pass: branchless off-diagonal fast path --------------------
__global__ __launch_bounds__(256, 2) void k_statsA(const u16* __restrict__ Qb,
                                                   const u16* __restrict__ Kb,
                                                   float* __restrict__ mpart,
                                                   float* __restrict__ lpart) {
  __shared__ __align__(16) u16 Qs[2][128 * 128];  // 2x32KB
  const int id = blockIdx.y * 64 + blockIdx.x;
  const int bb = id & 7, z = (id >> 3) & 7, sl = id >> 6;
  const int t = threadIdx.x, lane = t & 63, wj = (t >> 6) * 32;
  f32x4 zero = {0.f, 0.f, 0.f, 0.f};

  for (int ph = 0; ph < 2; ++ph) {
    const int jt = ph ? 15 - z : z;
    __syncthreads();
#pragma unroll
    for (int q = 0; q < 8; ++q) {
      int lin = q * 256 + t;
      gload16(Kb + ((size_t)bb * SEQ + jt * 128) * 128 + lin * 8, &Qs[0][lin * 8]);
    }
    __syncthreads();
    f16x8 af[2][4];
#pragma unroll
    for (int fj = 0; fj < 2; ++fj)
#pragma unroll
      for (int kk = 0; kk < 4; ++kk)
        af[fj][kk] = frag_ld<256>(Qs[0], wj + fj * 16 + (lane & 15), kk * 32 + (lane >> 4) * 8);
    float m[2][4], l[2][4];
#pragma unroll
    for (int a = 0; a < 2; ++a)
#pragma unroll
      for (int r = 0; r < 4; ++r) {
        m[a][r] = -INFINITY;
        l[a][r] = 0.f;
      }
    const int it0 = jt + ((sl - jt) & 7);
    int cur = 1;
    if (it0 < 16) {
#pragma unroll
      for (int q = 0; q < 8; ++q) {
        int lin = q * 256 + t;
        gload16(Qb + ((size_t)bb * SEQ + it0 * 128) * 128 + lin * 8, &Qs[1][lin * 8]);
      }
      for (int it = it0; it < 16; it += 8) {
        __syncthreads();
        if (it + 8 < 16) {
#pragma unroll
          for (int q = 0; q < 8; ++q) {
            int lin = q * 256 + t;
            gload16(Qb + ((size_t)bb * SEQ + (it + 8) * 128) * 128 + lin * 8,
                    &Qs[cur ^ 1][lin * 8]);
          }
        }
        f32x4 acc[2][8];
#pragma unroll
        for (int a = 0; a < 2; ++a)
#pragma unroll
          for (int b = 0; b < 8; ++b) acc[a][b] = zero;
        __builtin_amdgcn_s_setprio(1);
#pragma unroll
        for (int kk = 0; kk < 4; ++kk)
#pragma unroll
          for (int fi = 0; fi < 8; ++fi) {
            f16x8 bq = frag_ld<256>(Qs[cur], fi * 16 + (lane & 15), kk * 32 + (lane >> 4) * 8);
            acc[0][fi] = mfma16(af[0][kk], bq, acc[0][fi]);
            acc[1][fi] = mfma16(af[1][kk], bq, acc[1][fi]);
          }
        __builtin_amdgcn_s_setprio(0);
        if (it == jt) {  // diagonal tile: masked path with -inf guards
#pragma unroll
          for (int fj = 0; fj < 2; ++fj)
#pragma unroll
            for (int r = 0; r < 4; ++r) {
              int jg = jt * 128 + wj + fj * 16 + (lane >> 4) * 4 + r;
              float v[8];
              float vmax = -INFINITY;
#pragma unroll
              for (int fi = 0; fi < 8; ++fi) {
                int ig = it * 128 + fi * 16 + (lane & 15);
                v[fi] = (ig >= jg) ? acc[fj][fi][r] : -INFINITY;
                vmax = fmaxf(vmax, v[fi]);
              }
              if (vmax > -1e37f) {
                float mn = fmaxf(m[fj][r], vmax);
                float sc = (m[fj][r] > -1e37f) ? __expf(m[fj][r] - mn) : 0.f;
                float ss = 0.f;
#pragma unroll
                for (int fi = 0; fi < 8; ++fi)
                  ss += (v[fi] > -1e37f) ? __expf(v[fi] - mn) : 0.f;
                l[fj][r] = l[fj][r] * sc + ss;
                m[fj][r] = mn;
              }
            }
        } else {  // off-diagonal: all valid, branchless (exp(-inf)=0)
#pragma unroll
          for (int fj = 0; fj < 2; ++fj)
#pragma unroll
            for (int r = 0; r < 4; ++r) {
              float vmax = acc[fj][0][r];
#pragma unroll
              for (int fi = 1; fi < 8; ++fi) vmax = fmaxf(vmax, acc[fj][fi][r]);
              float mn = fmaxf(m[fj][r], vmax);
              float sc = __expf(m[fj][r] - mn);
              float ss = 0.f;
#pragma unroll
              for (int fi = 0; fi < 8; ++fi) ss += __expf(acc[fj][fi][r] - mn);
              l[fj][r] = l[fj][r] * sc + ss;
              m[fj][r] = mn;
            }
        }
        cur ^= 1;
      }
    }
#pragma unroll
    for (int fj = 0; fj < 2; ++fj)
#pragma unroll
      for (int r = 0; r < 4; ++r)
        for (int msk = 1; msk <= 8; msk <<= 1) {
          float m2 = __shfl_xor(m[fj][r], msk);
          float l2 = __shfl_xor(l[fj][r], msk);
          merge_ml(m[fj][r], l[fj][r], m2, l2);
        }
    if ((lane & 15) == 0) {
#pragma unroll
      for (int fj = 0; fj < 2; ++fj)
#pragma unroll
        for (int r = 0; r < 4; ++r) {
          int j = jt * 128 + wj + fj * 16 + (lane >> 4) * 4 + r;
          size_t idx = (size_t)sl * (NB * SEQ) + (size_t)bb * SEQ + j;
          mpart[idx] = m[fj][r];
          lpart[idx] = l[fj][r];
        }
    }
  }
}

// C_j = m_j + ln(l_j)
__global__ __launch_bounds__(256) void k_stats_reduce(const float* __restrict__ mpart,
                                                      const float* __restrict__ lpart,
                                                      float* __restrict__ Cg) {
  int idx = blockIdx.x * 256 + threadIdx.x;
  float m = -INFINITY;
#pragma unroll
  for (int sl = 0; sl < NSLS; sl++) m = fmaxf(m, mpart[sl * (NB * SEQ) + idx]);
  float l = 0.f;
#pragma unroll
  for (int sl = 0; sl < NSLS; sl++) {
    float ms = mpart[sl * (NB * SEQ) + idx];
    if (ms > -1e37f) l += lpart[sl * (NB * SEQ) + idx] * __expf(ms - m);
  }
  Cg[idx] = m + __logf(l);
}

// --------- PV pass: 64-row i-tiles, NSLP=4 slices, 512 balanced blocks -------
__global__ __launch_bounds__(256, 2) void k_passB(const u16* __restrict__ Qb,
                                                  const u16* __restrict__ Kb,
                                                  const u16* __restrict__ Vtb,
                                                  const float* __restrict__ Cg,
                                                  u16* __restrict__ opart) {
  __shared__ __align__(16) u16 Ks2[2][64 * 128];  // 2x16KB
  __shared__ __align__(16) u16 Vs2[2][128 * 64];  // 2x16KB
  __shared__ __align__(16) u16 Ps[64 * 64];       // 8KB (72KB total, 2 blk/CU)
  const int id = blockIdx.y * 64 + blockIdx.x;
  const int bb = id & 7, zp = (id >> 3) & 15, sl = id >> 7;
  const int t = threadIdx.x, lane = t & 63, wave = t >> 6;
  f32x4 zero = {0.f, 0.f, 0.f, 0.f};

  auto stageKV = [&](int jt, int b) {
#pragma unroll
    for (int q = 0; q < 4; ++q) {
      int lin = q * 256 + t;
      gload16(Kb + ((size_t)bb * SEQ + jt * 64) * 128 + lin * 8, &Ks2[b][lin * 8]);
    }
#pragma unroll
    for (int q = 0; q < 4; ++q) {
      int lin = q * 256 + t;
      gload16(Vtb + ((size_t)bb * 32 + jt) * 8192 + lin * 8, &Vs2[b][lin * 8]);
    }
  };

  for (int ph = 0; ph < 2; ++ph) {
    const int it = ph ? 31 - zp : zp;  // 64-row i-tile index
    f16x8 qf[4];
#pragma unroll
    for (int kk = 0; kk < 4; ++kk) {
      size_t gi = (size_t)bb * SEQ + it * 64 + wave * 16 + (lane & 15);
      int e0 = kk * 32 + (lane >> 4) * 8;
      qf[kk] = *reinterpret_cast<const f16x8*>(Qb + gi * 128 + (e0 ^ (((int)gi & 7) << 3)));
    }
    f32x4 accO[8];
#pragma unroll
    for (int b = 0; b < 8; ++b) accO[b] = zero;
    __syncthreads();  // prev-phase LDS readers done
    if (sl <= it) stageKV(sl, 0);
    int cur = 0;
    for (int jt = sl; jt <= it; jt += NSLP) {
      __syncthreads();  // stage(jt) landed; prev readers of cur done
      if (jt + NSLP <= it) stageKV(jt + NSLP, cur ^ 1);  // hides under QK+exp+PV
      float cj[4];
#pragma unroll
      for (int fj = 0; fj < 4; ++fj)
        cj[fj] = Cg[bb * SEQ + jt * 64 + fj * 16 + (lane & 15)];
      f32x4 accS[4];
#pragma unroll
      for (int b = 0; b < 4; ++b) accS[b] = zero;
      __builtin_amdgcn_s_setprio(1);
#pragma unroll
      for (int kk = 0; kk < 4; ++kk)
#pragma unroll
        for (int fj = 0; fj < 4; ++fj) {
          f16x8 bk = frag_ld<256>(Ks2[cur], fj * 16 + (lane & 15), kk * 32 + (lane >> 4) * 8);
          accS[fj] = mfma16(qf[kk], bk, accS[fj]);
        }
      __builtin_amdgcn_s_setprio(0);
      // P = exp(S - C_j), causal-masked; wave-private 16 rows of Ps
#pragma unroll
      for (int fj = 0; fj < 4; ++fj) {
        int jloc = fj * 16 + (lane & 15);
        int jg = jt * 64 + jloc;
        float c = cj[fj];
#pragma unroll
        for (int r = 0; r < 4; ++r) {
          int iloc = wave * 16 + (lane >> 4) * 4 + r;
          int ig = it * 64 + iloc;
          float p = __expf(accS[fj][r] - c);
          if (ig < jg) p = 0.f;
          Ps[iloc * 64 + (jloc ^ ((iloc & 7) << 3))] = f2h(p);
        }
      }
      // PV: wave-private P rows -> lgkm ordering only, no barrier
      __builtin_amdgcn_s_setprio(1);
#pragma unroll
      for (int ks = 0; ks < 2; ++ks) {
        f16x8 pa = frag_ld<128>(Ps, wave * 16 + (lane & 15), ks * 32 + (lane >> 4) * 8);
#pragma unroll
        for (int fh = 0; fh < 8; ++fh) {
          f16x8 bv = frag_ld<128>(Vs2[cur], fh * 16 + (lane & 15), ks * 32 + (lane >> 4) * 8);
          accO[fh] = mfma16(pa, bv, accO[fh]);
        }
      }
      __builtin_amdgcn_s_setprio(0);
      cur ^= 1;
    }
#pragma unroll
    for (int fh = 0; fh < 8; ++fh)
#pragma unroll
      for (int r = 0; r < 4; ++r) {
        int ig = it * 64 + wave * 16 + (lane >> 4) * 4 + r;
        int h = fh * 16 + (lane & 15);
        opart[(((size_t)sl * NB + bb) * SEQ + ig) * HD + h] = f2h(accO[fh][r]);
      }
  }
}

__global__ __launch_bounds__(256) void k_reduceB(const u16* __restrict__ opart,
                                                 float* __restrict__ out) {
  size_t base = ((size_t)blockIdx.x * 256 + threadIdx.x) * 8;
  const size_t S = (size_t)NB * SEQ * HD;
  float s[8];
#pragma unroll
  for (int j = 0; j < 8; j++) s[j] = 0.f;
#pragma unroll
  for (int sl = 0; sl < NSLP; sl++) {
    f16x8 v = *reinterpret_cast<const f16x8*>(opart + sl * S + base);
#pragma unroll
    for (int j = 0; j < 8; j++) s[j] += (float)v[j];
  }
  float4 o0 = {s[0], s[1], s[2], s[3]};
  float4 o1 = {s[4], s[5], s[6], s[7]};
  *reinterpret_cast<float4*>(out + base) = o0;
  *reinterpret_cast<float4*>(out + base + 4) = o1;
}

extern "C" void kernel_launch(void* const* d_in, const int* in_sizes, int n_in,
                              void* d_out, int out_size, void* d_ws, size_t ws_size,
                              hipStream_t stream) {
  (void)in_sizes; (void)n_in; (void)out_size; (void)ws_size;
  const float* x = (const float*)d_in[0];
  const float* Wk = (const float*)d_in[1];
  const float* Wq = (const float*)d_in[2];
  const float* Wv = (const float*)d_in[3];
  float* out = (float*)d_out;
  char* ws = (char*)d_ws;

  u16* Wt = (u16*)(ws + 0);                //   786,432 B  (pre-swizzled tiles)
  u16* Qb = (u16*)(ws + 786432);           // 4,194,304 B  (pre-swizzled)
  u16* Kb = (u16*)(ws + 4980736);          // 4,194,304 B  (pre-swizzled)
  u16* Vtb = (u16*)(ws + 9175040);         // 4,194,304 B  (pre-swizzled tiles)
  float* mpart = (float*)(ws + 13369344);  //   524,288 B
  float* lpart = (float*)(ws + 13893632);  //   524,288 B
  float* Cg = (float*)(ws + 14417920);     //    65,536 B
  u16* opart = (u16*)(ws + 14483456);      // 16,777,216 B (total ~31.3 MB)

  k_cvt_w<<<384, 256, 0, stream>>>(Wq, Wk, Wv, Wt);
  k_proj<<<dim3(256, 2), 512, 0, stream>>>(x, Wt, Qb, Kb, Vtb);
  k_statsA<<<dim3(64, 8), 256, 0, stream>>>(Qb, Kb, mpart, lpart);
  k_stats_reduce<<<64, 256, 0, stream>>>(mpart, lpart, Cg);
  k_passB<<<dim3(64, 8), 256, 0, stream>>>(Qb, Kb, Vtb, Cg, opart);
  k_reduceB<<<1024, 256, 0, stream>>>(opart, out);
}